// Round 2
// baseline (2253.752 us; speedup 1.0000x reference)
//
#include <hip/hip_runtime.h>

#define DEV static __device__ __forceinline__

DEV float sigm(float x){ return 1.f/(1.f + __expf(-x)); }
DEV float tanh_(float x){ float e = __expf(-2.f * x); return (1.f - e)/(1.f + e); }
DEV float dot4(float4 a, float4 b){ return a.x*b.x + a.y*b.y + a.z*b.z + a.w*b.w; }

// dims: B=64, T=64, P=32, H=256, 3H=768
// encoder: 10 steps over X[:,0:10,:]; decoder: 54 steps, dec_in[t] = (t==0) ? 0 : X[:,t+9,:]

// ===================== encoder =====================
// one WG per batch; thread j owns gate rows j, j+256, j+512
__global__ __launch_bounds__(256) void enc_kernel(
    const float* __restrict__ X, const float* __restrict__ Wih, const float* __restrict__ Whh,
    const float* __restrict__ bih, const float* __restrict__ bhh, float* __restrict__ h_out)
{
  const int b = blockIdx.x;
  const int j = threadIdx.x;
  __shared__ float h[256];
  __shared__ float xs[32];
  h[j] = 0.f;
  const float bir  = bih[j]     + bhh[j];
  const float biz  = bih[j+256] + bhh[j+256];
  const float bin_ = bih[j+512];
  const float bhn  = bhh[j+512];
  const float4* wr = (const float4*)(Whh + j*256);
  const float4* wz = (const float4*)(Whh + (j+256)*256);
  const float4* wn = (const float4*)(Whh + (j+512)*256);
  const float4* vr = (const float4*)(Wih + j*32);
  const float4* vz = (const float4*)(Wih + (j+256)*32);
  const float4* vn = (const float4*)(Wih + (j+512)*32);
  #pragma unroll 1
  for (int t = 0; t < 10; ++t) {
    __syncthreads();
    if (j < 32) xs[j] = X[b*2048 + t*32 + j];
    __syncthreads();
    float aR = 0.f, aZ = 0.f, aNh = 0.f, aNi = 0.f;
    #pragma unroll 4
    for (int c = 0; c < 64; ++c) {
      const float4 hv = ((const float4*)h)[c];
      aR  += dot4(wr[c], hv);
      aZ  += dot4(wz[c], hv);
      aNh += dot4(wn[c], hv);
    }
    #pragma unroll
    for (int c = 0; c < 8; ++c) {
      const float4 xv = ((const float4*)xs)[c];
      aR  += dot4(vr[c], xv);
      aZ  += dot4(vz[c], xv);
      aNi += dot4(vn[c], xv);
    }
    const float r  = sigm(aR + bir);
    const float zg = sigm(aZ + biz);
    const float nn = tanh_((aNi + bin_) + r*(aNh + bhn));
    const float hold = h[j];
    const float hn = (1.f - zg)*nn + zg*hold;
    __syncthreads();
    h[j] = hn;
    if (t == 9) h_out[b*256 + j] = hn;
  }
}

// ===================== latent (mu, log_var, z) =====================
__global__ __launch_bounds__(256) void lat_kernel(
    const float* __restrict__ h_enc,
    const float* __restrict__ Wmu, const float* __restrict__ bmu,
    const float* __restrict__ Wsd, const float* __restrict__ bsd,
    const float* __restrict__ eps,
    float* __restrict__ z, float* __restrict__ out_lv, float* __restrict__ out_mu)
{
  const int b = blockIdx.x, j = threadIdx.x;
  __shared__ float hs[256];
  hs[j] = h_enc[b*256 + j];
  __syncthreads();
  const float4* wm = (const float4*)(Wmu + j*256);
  const float4* ws = (const float4*)(Wsd + j*256);
  float am = 0.f, as = 0.f;
  #pragma unroll 4
  for (int c = 0; c < 64; ++c) {
    const float4 hv = ((const float4*)hs)[c];
    am += dot4(wm[c], hv);
    as += dot4(ws[c], hv);
  }
  const float mu = am + bmu[j];
  const float lv = as + bsd[j];
  const float zv = mu + __expf(0.5f*lv) * eps[b*256 + j];
  z[b*256 + j]      = zv;
  out_lv[b*256 + j] = lv;
  out_mu[b*256 + j] = mu;
}

// ===================== decoder =====================
// grid (8 batch-slices x 32 series); thread j owns gate rows j, j+256, j+512
// for 8 batch rows. LDS h reads are wave-uniform broadcasts.
__global__ __launch_bounds__(256) void dec_kernel(
    const float* __restrict__ X, const float* __restrict__ z,
    const float* __restrict__ Wih, const float* __restrict__ Whh,
    const float* __restrict__ bih, const float* __restrict__ bhh,
    const float* __restrict__ lin_w, const float* __restrict__ lin_b,
    float* __restrict__ pred)
{
  const int p   = blockIdx.y;       // series 0..31
  const int b0  = blockIdx.x * 8;   // batch base
  const int j   = threadIdx.x;      // hidden col 0..255

  __shared__ float h[8][256];
  __shared__ float xs[8][32];
  __shared__ float lws[256];
  __shared__ float ps[8][32];

  #pragma unroll
  for (int r = 0; r < 8; ++r)
    h[r][j] = z[(b0 + r)*256 + j];
  lws[j] = lin_w[p*256 + j];
  const float lb = lin_b[p];

  const float* WhhP = Whh + p*196608;
  const float* WihP = Wih + p*24576;
  const float bir  = bih[p*768 + j]       + bhh[p*768 + j];
  const float biz  = bih[p*768 + 256 + j] + bhh[p*768 + 256 + j];
  const float bin_ = bih[p*768 + 512 + j];
  const float bhn  = bhh[p*768 + 512 + j];
  const float4* wr = (const float4*)(WhhP + j*256);
  const float4* wz = (const float4*)(WhhP + (j+256)*256);
  const float4* wn = (const float4*)(WhhP + (j+512)*256);
  const float4* vr = (const float4*)(WihP + j*32);
  const float4* vz = (const float4*)(WihP + (j+256)*32);
  const float4* vn = (const float4*)(WihP + (j+512)*32);
  __syncthreads();

  #pragma unroll 1
  for (int t = 0; t < 54; ++t) {
    __syncthreads();                               // (a) protect xs/ps reuse
    {
      const int m = j >> 5, i = j & 31;
      xs[m][i] = (t == 0) ? 0.f : X[(b0 + m)*2048 + (t + 9)*32 + i];
    }
    __syncthreads();                               // (b) xs ready, h(t-1) ready

    float aR[8], aZ[8], aNh[8], aNi[8];
    #pragma unroll
    for (int m = 0; m < 8; ++m) { aR[m]=0.f; aZ[m]=0.f; aNh[m]=0.f; aNi[m]=0.f; }

    #pragma unroll 2
    for (int c = 0; c < 64; ++c) {
      const float4 w0 = wr[c];
      const float4 w1 = wz[c];
      const float4 w2 = wn[c];
      #pragma unroll
      for (int m = 0; m < 8; ++m) {
        const float4 hv = *(const float4*)&h[m][c*4];   // broadcast (lane-uniform)
        aR[m]  += dot4(w0, hv);
        aZ[m]  += dot4(w1, hv);
        aNh[m] += dot4(w2, hv);
      }
    }
    #pragma unroll
    for (int c = 0; c < 8; ++c) {
      const float4 v0 = vr[c];
      const float4 v1 = vz[c];
      const float4 v2 = vn[c];
      #pragma unroll
      for (int m = 0; m < 8; ++m) {
        const float4 xv = *(const float4*)&xs[m][c*4];  // broadcast
        aR[m]  += dot4(v0, xv);
        aZ[m]  += dot4(v1, xv);
        aNi[m] += dot4(v2, xv);
      }
    }

    float hn[8];
    #pragma unroll
    for (int m = 0; m < 8; ++m) {
      const float r  = sigm(aR[m] + bir);
      const float zg = sigm(aZ[m] + biz);
      const float nn = tanh_((aNi[m] + bin_) + r*(aNh[m] + bhn));
      hn[m] = (1.f - zg)*nn + zg*h[m][j];
    }
    __syncthreads();                               // (c) gate reads of h done
    #pragma unroll
    for (int m = 0; m < 8; ++m)
      h[m][j] = hn[m];
    __syncthreads();                               // (d) h(t) complete

    {
      const int m = j >> 5, kg = j & 31;
      const float4 a  = *(const float4*)&h[m][kg*8];
      const float4 b2 = *(const float4*)&h[m][kg*8 + 4];
      const float4 l0 = *(const float4*)&lws[kg*8];
      const float4 l1 = *(const float4*)&lws[kg*8 + 4];
      ps[m][kg] = dot4(a, l0) + dot4(b2, l1);
    }
    __syncthreads();                               // (e) ps ready
    if (j < 8) {
      float s = lb;
      #pragma unroll
      for (int i2 = 0; i2 < 32; ++i2) s += ps[j][i2];
      pred[p*3456 + (b0 + j)*54 + t] = s;          // pred[p][b][t][0], 3456 = 64*54
    }
  }
}

extern "C" void kernel_launch(void* const* d_in, const int* in_sizes, int n_in,
                              void* d_out, int out_size, void* d_ws, size_t ws_size,
                              hipStream_t stream) {
  const float* X        = (const float*)d_in[0];
  const float* eps      = (const float*)d_in[1];
  const float* Wih_enc  = (const float*)d_in[2];
  const float* Whh_enc  = (const float*)d_in[3];
  const float* bih_enc  = (const float*)d_in[4];
  const float* bhh_enc  = (const float*)d_in[5];
  const float* fc_mu_w  = (const float*)d_in[6];
  const float* fc_mu_b  = (const float*)d_in[7];
  const float* fc_std_w = (const float*)d_in[8];
  const float* fc_std_b = (const float*)d_in[9];
  const float* Wih_dec  = (const float*)d_in[10];
  const float* Whh_dec  = (const float*)d_in[11];
  const float* bih_dec  = (const float*)d_in[12];
  const float* bhh_dec  = (const float*)d_in[13];
  const float* lin_w    = (const float*)d_in[14];
  const float* lin_b    = (const float*)d_in[15];

  float* out    = (float*)d_out;
  float* pred   = out;              // [32][64][54][1] = 110592
  float* out_lv = out + 110592;     // [1][64][256]
  float* out_mu = out + 126976;     // [1][64][256]

  float* h_enc = (float*)d_ws;      // [64][256] fp32
  float* z     = h_enc + 16384;     // [64][256] fp32

  enc_kernel<<<64, 256, 0, stream>>>(X, Wih_enc, Whh_enc, bih_enc, bhh_enc, h_enc);
  lat_kernel<<<64, 256, 0, stream>>>(h_enc, fc_mu_w, fc_mu_b, fc_std_w, fc_std_b, eps,
                                     z, out_lv, out_mu);
  dec_kernel<<<dim3(8, 32), 256, 0, stream>>>(X, z, Wih_dec, Whh_dec, bih_dec, bhh_dec,
                                              lin_w, lin_b, pred);
}

// Round 3
// 1012.080 us; speedup vs baseline: 2.2269x; 2.2269x over previous
//
#include <hip/hip_runtime.h>

typedef unsigned int u32;
typedef unsigned short u16;
typedef __attribute__((ext_vector_type(8))) short short8;
typedef __attribute__((ext_vector_type(4))) float f32x4;

#define DEV static __device__ __forceinline__

DEV float b2f(u16 v){ union{u32 u; float f;} c; c.u = ((u32)v) << 16; return c.f; }
DEV u16 f2b(float f){ union{float ff; u32 u;} c; c.ff = f; return (u16)((c.u + 0x7fffu + ((c.u >> 16) & 1u)) >> 16); }
DEV float sigm(float x){ return 1.f/(1.f + __expf(-x)); }
DEV float tanh_(float x){ float e = __expf(-2.f*x); return (1.f-e)/(1.f+e); }
DEV float dot4(float4 a, float4 b){ return a.x*b.x + a.y*b.y + a.z*b.z + a.w*b.w; }

// dims: B=64, T=64, P=32, H=256, 3H=768.
// B-pack: per series: 48 N-tiles x 9 K-tiles (8 h-tiles K=32 + 1 x-tile K=32) x 64 lanes x 8 bf16.
// series stride = 48*9*64*8 = 221184 u16 (442368 B). 33 series (32 dec + enc) = 14.6 MB.
#define SER_STRIDE 221184

// ===================== fragment pack =====================
__global__ __launch_bounds__(64) void pack_kernel(
    const float* __restrict__ WihD, const float* __restrict__ WhhD,
    const float* __restrict__ WihE, const float* __restrict__ WhhE,
    u16* __restrict__ wsB)
{
  const int ps = blockIdx.y;           // 0..31 dec series, 32 = encoder
  const int f  = blockIdx.x;           // n0*9 + k, 0..431
  const int n0 = f / 9, k = f - n0*9;
  const int lane = threadIdx.x;
  const int n = lane & 15, q = lane >> 4;
  const int row = n0*16 + n;
  const float* Whh = (ps < 32) ? WhhD + ps*196608 : WhhE;
  const float* Wih = (ps < 32) ? WihD + ps*24576  : WihE;
  const float* src = (k < 8) ? (Whh + row*256 + k*32 + q*8) : (Wih + row*32 + q*8);
  u32 wd[4];
  #pragma unroll
  for (int j = 0; j < 4; ++j) {
    u16 lo = f2b(src[2*j]);
    u16 hi = f2b(src[2*j+1]);
    wd[j] = (u32)lo | ((u32)hi << 16);
  }
  uint4* dst = (uint4*)(wsB + (((size_t)ps*432 + f)*64 + lane)*8);
  *dst = make_uint4(wd[0], wd[1], wd[2], wd[3]);
}

// ===================== GRU body (MFMA) =====================
// block = 256 thr = 4 waves. WG covers M=16 batches (b0..b0+15), N=768 gate rows.
// wave w owns gate cols [w*64, w*64+64): r-tiles w*4+i, z-tiles 16+w*4+i, n-tiles 32+w*4+i.
template<int NSTEPS, bool IS_DEC>
DEV void gru_body(const u16* __restrict__ Bp, const float* __restrict__ X,
                  const float* __restrict__ h0,
                  const float* __restrict__ bih, const float* __restrict__ bhh,
                  const float* __restrict__ lwp, const float* __restrict__ lbp,
                  float* __restrict__ predp, float* __restrict__ hout, int b0)
{
  __shared__ u16 hx[16][288];          // [batch][h(256) | x(32)] bf16
  __shared__ float lws[256];
  __shared__ float psum[16][16];
  const int tid = threadIdx.x;
  const int w = tid >> 6, lane = tid & 63;
  const int n = lane & 15, q = lane >> 4;

  #pragma unroll
  for (int r = 0; r < 16; ++r) {
    int idx = r*256 + tid;
    int m = idx >> 8, c = idx & 255;
    hx[m][c] = IS_DEC ? f2b(h0[(b0+m)*256 + c]) : (u16)0;
  }
  float lb = 0.f;
  if (IS_DEC) { lws[tid] = lwp[tid]; lb = lbp[0]; }

  float br[4], bz[4], bnx[4], bnh[4];
  #pragma unroll
  for (int i = 0; i < 4; ++i) {
    const int col = w*64 + i*16 + n;
    br[i]  = bih[col]       + bhh[col];
    bz[i]  = bih[256 + col] + bhh[256 + col];
    bnx[i] = bih[512 + col];
    bnh[i] = bhh[512 + col];
  }

  #pragma unroll 1
  for (int t = 0; t < NSTEPS; ++t) {
    {
      const int idx = tid*2;
      const int m = idx >> 5, c2 = idx & 31;
      float v0, v1;
      if (IS_DEC) {
        const bool z0 = (t == 0);
        v0 = z0 ? 0.f : X[(b0+m)*2048 + (t+9)*32 + c2];
        v1 = z0 ? 0.f : X[(b0+m)*2048 + (t+9)*32 + c2 + 1];
      } else {
        v0 = X[(b0+m)*2048 + t*32 + c2];
        v1 = X[(b0+m)*2048 + t*32 + c2 + 1];
      }
      hx[m][256+c2]   = f2b(v0);
      hx[m][256+c2+1] = f2b(v1);
    }
    __syncthreads();                               // (1) x ready, h(t-1) ready

    short8 af[9];                                   // A-frags: A[m=n][k=q*8+j]
    #pragma unroll
    for (int k0 = 0; k0 < 8; ++k0)
      af[k0] = *(const short8*)&hx[n][k0*32 + q*8];
    af[8] = *(const short8*)&hx[n][256 + q*8];

    float hnew[4][4];
    #pragma unroll 1
    for (int i = 0; i < 4; ++i) {
      const int nr = w*4 + i;
      f32x4 ar = {0,0,0,0}, az = {0,0,0,0}, anh = {0,0,0,0}, anx = {0,0,0,0};
      const u16* Br = Bp + ((size_t)(nr       *9)*64 + lane)*8;
      const u16* Bz = Bp + ((size_t)((16+nr)  *9)*64 + lane)*8;
      const u16* Bn = Bp + ((size_t)((32+nr)  *9)*64 + lane)*8;
      #pragma unroll
      for (int k0 = 0; k0 < 9; ++k0) {
        const short8 bfr = *(const short8*)(Br + k0*512);
        const short8 bfz = *(const short8*)(Bz + k0*512);
        const short8 bfn = *(const short8*)(Bn + k0*512);
        ar = __builtin_amdgcn_mfma_f32_16x16x32_bf16(af[k0], bfr, ar, 0, 0, 0);
        az = __builtin_amdgcn_mfma_f32_16x16x32_bf16(af[k0], bfz, az, 0, 0, 0);
        if (k0 < 8) anh = __builtin_amdgcn_mfma_f32_16x16x32_bf16(af[k0], bfn, anh, 0, 0, 0);
        else        anx = __builtin_amdgcn_mfma_f32_16x16x32_bf16(af[8],  bfn, anx, 0, 0, 0);
      }
      #pragma unroll
      for (int rr = 0; rr < 4; ++rr) {
        const int m = q*4 + rr;                    // D: row=(lane>>4)*4+reg, col=lane&15
        const float rg = sigm(ar[rr] + br[i]);
        const float zg = sigm(az[rr] + bz[i]);
        const float nv = tanh_(anx[rr] + bnx[i] + rg*(anh[rr] + bnh[i]));
        const float hold = b2f(hx[m][w*64 + i*16 + n]);
        hnew[i][rr] = (1.f - zg)*nv + zg*hold;
      }
    }
    __syncthreads();                               // (2) all reads of h(t-1) done
    #pragma unroll
    for (int i = 0; i < 4; ++i)
      #pragma unroll
      for (int rr = 0; rr < 4; ++rr)
        hx[q*4 + rr][w*64 + i*16 + n] = f2b(hnew[i][rr]);
    __syncthreads();                               // (3) h(t) complete

    if (IS_DEC) {
      const int m = tid >> 4, seg = tid & 15;
      float s = 0.f;
      #pragma unroll
      for (int c = 0; c < 16; ++c)
        s += b2f(hx[m][seg*16 + c]) * lws[seg*16 + c];
      psum[m][seg] = s;
      __syncthreads();                             // (4) psum ready
      if (tid < 16) {
        float s2 = lb;
        #pragma unroll
        for (int c = 0; c < 16; ++c) s2 += psum[tid][c];
        predp[(b0 + tid)*54 + t] = s2;
      }
    }
  }
  if (!IS_DEC) {
    #pragma unroll
    for (int r = 0; r < 16; ++r) {
      int idx = r*256 + tid;
      int m = idx >> 8, c = idx & 255;
      hout[(b0+m)*256 + c] = b2f(hx[m][c]);
    }
  }
}

__global__ __launch_bounds__(256) void enc_mfma(
    const u16* __restrict__ wsB, const float* __restrict__ X,
    const float* __restrict__ bih, const float* __restrict__ bhh,
    float* __restrict__ h_out)
{
  gru_body<10, false>(wsB + (size_t)32*SER_STRIDE, X, nullptr, bih, bhh,
                      nullptr, nullptr, nullptr, h_out, blockIdx.x*16);
}

// grid (32 p, 4 s): linear id = p + 32*s -> all slices of series p on XCD p%8 (L2 locality)
__global__ __launch_bounds__(256) void dec_mfma(
    const u16* __restrict__ wsB, const float* __restrict__ X,
    const float* __restrict__ z,
    const float* __restrict__ bih, const float* __restrict__ bhh,
    const float* __restrict__ lin_w, const float* __restrict__ lin_b,
    float* __restrict__ pred)
{
  const int p = blockIdx.x;
  gru_body<54, true>(wsB + (size_t)p*SER_STRIDE, X, z, bih + p*768, bhh + p*768,
                     lin_w + p*256, lin_b + p, pred + p*3456, nullptr, blockIdx.y*16);
}

// ===================== latent (mu, log_var, z) =====================
__global__ __launch_bounds__(256) void lat_kernel(
    const float* __restrict__ h_enc,
    const float* __restrict__ Wmu, const float* __restrict__ bmu,
    const float* __restrict__ Wsd, const float* __restrict__ bsd,
    const float* __restrict__ eps,
    float* __restrict__ z, float* __restrict__ out_lv, float* __restrict__ out_mu)
{
  const int b = blockIdx.x, j = threadIdx.x;
  __shared__ float hs[256];
  hs[j] = h_enc[b*256 + j];
  __syncthreads();
  const float4* wm = (const float4*)(Wmu + j*256);
  const float4* ws = (const float4*)(Wsd + j*256);
  float am = 0.f, as = 0.f;
  #pragma unroll 4
  for (int c = 0; c < 64; ++c) {
    const float4 hv = ((const float4*)hs)[c];
    am += dot4(wm[c], hv);
    as += dot4(ws[c], hv);
  }
  const float mu = am + bmu[j];
  const float lv = as + bsd[j];
  const float zv = mu + __expf(0.5f*lv) * eps[b*256 + j];
  z[b*256 + j]      = zv;
  out_lv[b*256 + j] = lv;
  out_mu[b*256 + j] = mu;
}

extern "C" void kernel_launch(void* const* d_in, const int* in_sizes, int n_in,
                              void* d_out, int out_size, void* d_ws, size_t ws_size,
                              hipStream_t stream) {
  const float* X        = (const float*)d_in[0];
  const float* eps      = (const float*)d_in[1];
  const float* Wih_enc  = (const float*)d_in[2];
  const float* Whh_enc  = (const float*)d_in[3];
  const float* bih_enc  = (const float*)d_in[4];
  const float* bhh_enc  = (const float*)d_in[5];
  const float* fc_mu_w  = (const float*)d_in[6];
  const float* fc_mu_b  = (const float*)d_in[7];
  const float* fc_std_w = (const float*)d_in[8];
  const float* fc_std_b = (const float*)d_in[9];
  const float* Wih_dec  = (const float*)d_in[10];
  const float* Whh_dec  = (const float*)d_in[11];
  const float* bih_dec  = (const float*)d_in[12];
  const float* bhh_dec  = (const float*)d_in[13];
  const float* lin_w    = (const float*)d_in[14];
  const float* lin_b    = (const float*)d_in[15];

  float* out    = (float*)d_out;
  float* pred   = out;              // [32][64][54][1] = 110592
  float* out_lv = out + 110592;     // [1][64][256]
  float* out_mu = out + 126976;     // [1][64][256]

  u16*   wsB   = (u16*)d_ws;                       // 33 * 221184 u16 = 14.6 MB
  float* h_enc = (float*)((char*)d_ws + (size_t)33*SER_STRIDE*2);  // [64][256]
  float* z     = h_enc + 16384;                    // [64][256]

  pack_kernel<<<dim3(432, 33), 64, 0, stream>>>(Wih_dec, Whh_dec, Wih_enc, Whh_enc, wsB);
  enc_mfma<<<4, 256, 0, stream>>>(wsB, X, bih_enc, bhh_enc, h_enc);
  lat_kernel<<<64, 256, 0, stream>>>(h_enc, fc_mu_w, fc_mu_b, fc_std_w, fc_std_b, eps,
                                     z, out_lv, out_mu);
  dec_mfma<<<dim3(32, 4), 256, 0, stream>>>(wsB, X, z, bih_dec, bhh_dec,
                                            lin_w, lin_b, pred);
}

// Round 4
// 423.258 us; speedup vs baseline: 5.3248x; 2.3912x over previous
//
#include <hip/hip_runtime.h>

typedef unsigned int u32;
typedef unsigned short u16;
typedef __attribute__((ext_vector_type(8))) short short8;
typedef __attribute__((ext_vector_type(4))) float f32x4;

#define DEV static __device__ __forceinline__

DEV float b2f(u16 v){ union{u32 u; float f;} c; c.u = ((u32)v) << 16; return c.f; }
DEV u16 f2b(float f){ union{float ff; u32 u;} c; c.ff = f; return (u16)((c.u + 0x7fffu + ((c.u >> 16) & 1u)) >> 16); }
DEV float sigm(float x){ return 1.f/(1.f + __expf(-x)); }
DEV float tanh_(float x){ float e = __expf(-2.f*x); return (1.f-e)/(1.f+e); }
DEV float dot4(float4 a, float4 b){ return a.x*b.x + a.y*b.y + a.z*b.z + a.w*b.w; }

// dims: B=64, T=64, P=32, H=256, 3H=768.
// B-pack: per series: 48 N-tiles x 9 K-tiles (8 h-tiles K=32 + 1 x-tile K=32) x 64 lanes x 8 bf16.
#define SER_STRIDE 221184   // u16 per series = 48*9*64*8

// ===================== fragment pack (unchanged layout) =====================
__global__ __launch_bounds__(64) void pack_kernel(
    const float* __restrict__ WihD, const float* __restrict__ WhhD,
    const float* __restrict__ WihE, const float* __restrict__ WhhE,
    u16* __restrict__ wsB)
{
  const int ps = blockIdx.y;           // 0..31 dec series, 32 = encoder
  const int f  = blockIdx.x;           // n0*9 + k, 0..431
  const int n0 = f / 9, k = f - n0*9;
  const int lane = threadIdx.x;
  const int n = lane & 15, q = lane >> 4;
  const int row = n0*16 + n;
  const float* Whh = (ps < 32) ? WhhD + ps*196608 : WhhE;
  const float* Wih = (ps < 32) ? WihD + ps*24576  : WihE;
  const float* src = (k < 8) ? (Whh + row*256 + k*32 + q*8) : (Wih + row*32 + q*8);
  u32 wd[4];
  #pragma unroll
  for (int j = 0; j < 4; ++j) {
    u16 lo = f2b(src[2*j]);
    u16 hi = f2b(src[2*j+1]);
    wd[j] = (u32)lo | ((u32)hi << 16);
  }
  uint4* dst = (uint4*)(wsB + (((size_t)ps*432 + f)*64 + lane)*8);
  *dst = make_uint4(wd[0], wd[1], wd[2], wd[3]);
}

// ===================== GRU body (MFMA, register-resident B) =====================
// block = 256 thr = 4 waves, M=16 batches. Wave w owns hidden cols [w*64, w*64+64)
// = col-tiles i=0..3 (N-tiles g*16 + w*4 + i for gates g=r,z,n).
// B residency: K-tiles 0..5 in VGPRs (72 frags), K-tile 8 (x) in LDS (once),
// K-tiles 6..7 streamed from L2 per step (double-buffered, issued pre-barrier).
template<int NSTEPS, bool IS_DEC>
DEV void gru_body(const u16* __restrict__ Bp, const float* __restrict__ X,
                  const float* __restrict__ h0,
                  const float* __restrict__ bih, const float* __restrict__ bhh,
                  const float* __restrict__ lwp, const float* __restrict__ lbp,
                  float* __restrict__ predp, float* __restrict__ hout, int b0)
{
  __shared__ u16 hx[16][290];          // [batch][h(256) | x(32) | pad(2)] stride=145 dwords
  __shared__ u16 Bx[48*64*8];          // K-tile 8 (x-part) frags, 48 KB, loaded once
  __shared__ float lws[256];
  __shared__ float psum[16][16];
  const int tid = threadIdx.x;
  const int w = tid >> 6, lane = tid & 63;
  const int n = lane & 15, q = lane >> 4;

  // init h (bf16) from h0 / zeros
  #pragma unroll
  for (int r = 0; r < 16; ++r) {
    int idx = r*256 + tid;
    int m = idx >> 8, c = idx & 255;
    hx[m][c] = IS_DEC ? f2b(h0[(b0+m)*256 + c]) : (u16)0;
  }
  float lb = 0.f;
  if (IS_DEC) { lws[tid] = lwp[tid]; lb = lbp[0]; }

  // stage x-part B frags into LDS (once)
  #pragma unroll
  for (int r = 0; r < 12; ++r) {
    int f = r*256 + tid;               // n0*64 + l
    int n0 = f >> 6, l = f & 63;
    ((uint4*)Bx)[f] = *(const uint4*)(Bp + (((size_t)n0*9 + 8)*64 + l)*8);
  }

  // resident B: K-tiles 0..5 for the wave's 12 N-tiles
  short8 Bres[72];
  #pragma unroll
  for (int i = 0; i < 4; ++i)
    #pragma unroll
    for (int g = 0; g < 3; ++g)
      #pragma unroll
      for (int k = 0; k < 6; ++k)
        Bres[(i*3+g)*6+k] =
          *(const short8*)(Bp + ((((size_t)(g*16 + w*4 + i))*9 + k)*64 + lane)*8);

  // per-lane biases for owned cols (col = (w*4+i)*16 + n)
  float br[4], bz[4], bnx[4], bnh[4];
  #pragma unroll
  for (int i = 0; i < 4; ++i) {
    const int col = (w*4 + i)*16 + n;
    br[i]  = bih[col]       + bhh[col];
    bz[i]  = bih[256 + col] + bhh[256 + col];
    bnx[i] = bih[512 + col];
    bnh[i] = bhh[512 + col];
  }

  short8 Sbuf[2][6];                   // streamed K6,K7 double buffer
  #define ISSUE(ii, par)                                                         \
    { _Pragma("unroll")                                                          \
      for (int g = 0; g < 3; ++g) {                                              \
        _Pragma("unroll")                                                        \
        for (int kk = 0; kk < 2; ++kk)                                           \
          Sbuf[par][g*2+kk] =                                                    \
            *(const short8*)(Bp + ((((size_t)(g*16 + w*4 + (ii)))*9 + 6+kk)*64 + lane)*8); \
      } }

  #pragma unroll 1
  for (int t = 0; t < NSTEPS; ++t) {
    ISSUE(0, 0)                        // step-invariant addresses: issue before barrier
    {
      const int idx = tid*2;
      const int m = idx >> 5, c2 = idx & 31;
      float v0, v1;
      if (IS_DEC) {
        const bool z0 = (t == 0);
        v0 = z0 ? 0.f : X[(b0+m)*2048 + (t+9)*32 + c2];
        v1 = z0 ? 0.f : X[(b0+m)*2048 + (t+9)*32 + c2 + 1];
      } else {
        v0 = X[(b0+m)*2048 + t*32 + c2];
        v1 = X[(b0+m)*2048 + t*32 + c2 + 1];
      }
      hx[m][256+c2]   = f2b(v0);
      hx[m][256+c2+1] = f2b(v1);
    }
    __syncthreads();                   // (1) x staged, h(t-1) ready

    short8 af[9];                      // A-frags: A[m=n][k=q*8+j]
    #pragma unroll
    for (int k0 = 0; k0 < 8; ++k0)
      af[k0] = *(const short8*)&hx[n][k0*32 + q*8];
    af[8] = *(const short8*)&hx[n][256 + q*8];

    float hnew[4][4];
    #pragma unroll
    for (int i = 0; i < 4; ++i) {
      if (i < 3) ISSUE(i+1, (i+1)&1)   // prefetch next col-tile's streamed frags
      f32x4 ar = {0,0,0,0}, az = {0,0,0,0}, anh = {0,0,0,0}, anx = {0,0,0,0};
      #pragma unroll
      for (int k = 0; k < 6; ++k) {
        ar  = __builtin_amdgcn_mfma_f32_16x16x32_bf16(af[k], Bres[(i*3+0)*6+k], ar, 0,0,0);
        az  = __builtin_amdgcn_mfma_f32_16x16x32_bf16(af[k], Bres[(i*3+1)*6+k], az, 0,0,0);
        anh = __builtin_amdgcn_mfma_f32_16x16x32_bf16(af[k], Bres[(i*3+2)*6+k], anh, 0,0,0);
      }
      #pragma unroll
      for (int kk = 0; kk < 2; ++kk) {
        ar  = __builtin_amdgcn_mfma_f32_16x16x32_bf16(af[6+kk], Sbuf[i&1][0*2+kk], ar, 0,0,0);
        az  = __builtin_amdgcn_mfma_f32_16x16x32_bf16(af[6+kk], Sbuf[i&1][1*2+kk], az, 0,0,0);
        anh = __builtin_amdgcn_mfma_f32_16x16x32_bf16(af[6+kk], Sbuf[i&1][2*2+kk], anh, 0,0,0);
      }
      {
        const int nt = w*4 + i;
        const short8 bxr = *(const short8*)&Bx[(( 0+nt)*64 + lane)*8];
        const short8 bxz = *(const short8*)&Bx[((16+nt)*64 + lane)*8];
        const short8 bxn = *(const short8*)&Bx[((32+nt)*64 + lane)*8];
        ar  = __builtin_amdgcn_mfma_f32_16x16x32_bf16(af[8], bxr, ar, 0,0,0);
        az  = __builtin_amdgcn_mfma_f32_16x16x32_bf16(af[8], bxz, az, 0,0,0);
        anx = __builtin_amdgcn_mfma_f32_16x16x32_bf16(af[8], bxn, anx, 0,0,0);
      }
      #pragma unroll
      for (int rr = 0; rr < 4; ++rr) {
        const int m = q*4 + rr;        // D: row=(lane>>4)*4+reg, col=lane&15
        const float rg = sigm(ar[rr] + br[i]);
        const float zg = sigm(az[rr] + bz[i]);
        const float nv = tanh_(anx[rr] + bnx[i] + rg*(anh[rr] + bnh[i]));
        const float hold = b2f(hx[m][(w*4+i)*16 + n]);
        hnew[i][rr] = (1.f - zg)*nv + zg*hold;
      }
    }
    __syncthreads();                   // (2) all reads of h(t-1) done
    #pragma unroll
    for (int i = 0; i < 4; ++i)
      #pragma unroll
      for (int rr = 0; rr < 4; ++rr)
        hx[q*4 + rr][(w*4+i)*16 + n] = f2b(hnew[i][rr]);
    __syncthreads();                   // (3) h(t) complete

    if (IS_DEC) {
      const int m = tid >> 4, seg = tid & 15;
      float s = 0.f;
      #pragma unroll
      for (int c = 0; c < 16; ++c)
        s += b2f(hx[m][seg*16 + c]) * lws[seg*16 + c];
      psum[m][seg] = s;
      __syncthreads();                 // (4) psum ready
      if (tid < 16) {
        float s2 = lb;
        #pragma unroll
        for (int c = 0; c < 16; ++c) s2 += psum[tid][c];
        predp[(b0 + tid)*54 + t] = s2;
      }
    }
  }
  if (!IS_DEC) {
    #pragma unroll
    for (int r = 0; r < 16; ++r) {
      int idx = r*256 + tid;
      int m = idx >> 8, c = idx & 255;
      hout[(b0+m)*256 + c] = b2f(hx[m][c]);
    }
  }
  #undef ISSUE
}

__global__ __launch_bounds__(256, 1) void enc_mfma(
    const u16* __restrict__ wsB, const float* __restrict__ X,
    const float* __restrict__ bih, const float* __restrict__ bhh,
    float* __restrict__ h_out)
{
  gru_body<10, false>(wsB + (size_t)32*SER_STRIDE, X, nullptr, bih, bhh,
                      nullptr, nullptr, nullptr, h_out, blockIdx.x*16);
}

// grid (32 p, 4 s): linear id = p + 32*s -> all slices of series p on XCD p%8
__global__ __launch_bounds__(256, 1) void dec_mfma(
    const u16* __restrict__ wsB, const float* __restrict__ X,
    const float* __restrict__ z,
    const float* __restrict__ bih, const float* __restrict__ bhh,
    const float* __restrict__ lin_w, const float* __restrict__ lin_b,
    float* __restrict__ pred)
{
  const int p = blockIdx.x;
  gru_body<54, true>(wsB + (size_t)p*SER_STRIDE, X, z, bih + p*768, bhh + p*768,
                     lin_w + p*256, lin_b + p, pred + p*3456, nullptr, blockIdx.y*16);
}

// ===================== latent (mu, log_var, z) =====================
__global__ __launch_bounds__(256) void lat_kernel(
    const float* __restrict__ h_enc,
    const float* __restrict__ Wmu, const float* __restrict__ bmu,
    const float* __restrict__ Wsd, const float* __restrict__ bsd,
    const float* __restrict__ eps,
    float* __restrict__ z, float* __restrict__ out_lv, float* __restrict__ out_mu)
{
  const int b = blockIdx.x, j = threadIdx.x;
  __shared__ float hs[256];
  hs[j] = h_enc[b*256 + j];
  __syncthreads();
  const float4* wm = (const float4*)(Wmu + j*256);
  const float4* ws = (const float4*)(Wsd + j*256);
  float am = 0.f, as = 0.f;
  #pragma unroll 4
  for (int c = 0; c < 64; ++c) {
    const float4 hv = ((const float4*)hs)[c];
    am += dot4(wm[c], hv);
    as += dot4(ws[c], hv);
  }
  const float mu = am + bmu[j];
  const float lv = as + bsd[j];
  const float zv = mu + __expf(0.5f*lv) * eps[b*256 + j];
  z[b*256 + j]      = zv;
  out_lv[b*256 + j] = lv;
  out_mu[b*256 + j] = mu;
}

extern "C" void kernel_launch(void* const* d_in, const int* in_sizes, int n_in,
                              void* d_out, int out_size, void* d_ws, size_t ws_size,
                              hipStream_t stream) {
  const float* X        = (const float*)d_in[0];
  const float* eps      = (const float*)d_in[1];
  const float* Wih_enc  = (const float*)d_in[2];
  const float* Whh_enc  = (const float*)d_in[3];
  const float* bih_enc  = (const float*)d_in[4];
  const float* bhh_enc  = (const float*)d_in[5];
  const float* fc_mu_w  = (const float*)d_in[6];
  const float* fc_mu_b  = (const float*)d_in[7];
  const float* fc_std_w = (const float*)d_in[8];
  const float* fc_std_b = (const float*)d_in[9];
  const float* Wih_dec  = (const float*)d_in[10];
  const float* Whh_dec  = (const float*)d_in[11];
  const float* bih_dec  = (const float*)d_in[12];
  const float* bhh_dec  = (const float*)d_in[13];
  const float* lin_w    = (const float*)d_in[14];
  const float* lin_b    = (const float*)d_in[15];

  float* out    = (float*)d_out;
  float* pred   = out;              // [32][64][54][1] = 110592
  float* out_lv = out + 110592;     // [1][64][256]
  float* out_mu = out + 126976;     // [1][64][256]

  u16*   wsB   = (u16*)d_ws;                       // 33 * 221184 u16 = 14.6 MB
  float* h_enc = (float*)((char*)d_ws + (size_t)33*SER_STRIDE*2);  // [64][256]
  float* z     = h_enc + 16384;                    // [64][256]

  pack_kernel<<<dim3(432, 33), 64, 0, stream>>>(Wih_dec, Whh_dec, Wih_enc, Whh_enc, wsB);
  enc_mfma<<<4, 256, 0, stream>>>(wsB, X, bih_enc, bhh_enc, h_enc);
  lat_kernel<<<64, 256, 0, stream>>>(h_enc, fc_mu_w, fc_mu_b, fc_std_w, fc_std_b, eps,
                                     z, out_lv, out_mu);
  dec_mfma<<<dim3(32, 4), 256, 0, stream>>>(wsB, X, z, bih_dec, bhh_dec,
                                            lin_w, lin_b, pred);
}

// Round 5
// 396.851 us; speedup vs baseline: 5.6791x; 1.0665x over previous
//
#include <hip/hip_runtime.h>

typedef unsigned int u32;
typedef unsigned short u16;
typedef __attribute__((ext_vector_type(8))) short short8;
typedef __attribute__((ext_vector_type(4))) float f32x4;

#define DEV static __device__ __forceinline__

DEV float b2f(u16 v){ union{u32 u; float f;} c; c.u = ((u32)v) << 16; return c.f; }
DEV u16 f2b(float f){ union{float ff; u32 u;} c; c.ff = f; return (u16)((c.u + 0x7fffu + ((c.u >> 16) & 1u)) >> 16); }
DEV float sigm(float x){ return 1.f/(1.f + __expf(-x)); }
DEV float tanh_(float x){ float e = __expf(-2.f*x); return (1.f-e)/(1.f+e); }
DEV float dot4(float4 a, float4 b){ return a.x*b.x + a.y*b.y + a.z*b.z + a.w*b.w; }

// dims: B=64, T=64, P=32, H=256, 3H=768.
// hx row stride: 328 u16 = 164 dwords; 164 % 32 == 4 -> A-frag ds_read_b128
// start banks spaced 4 apart per 8-lane phase -> conflict-free.
#define RS 328
// LDS layout (dynamic): hx[16][RS] u16 (10496 B) | Blds 48*3 frags x 1KB (147456 B) | psum[8][8] f32
#define HX_BYTES   (16*RS*2)
#define BLDS_BYTES (48*3*64*16)
#define SMEM_BYTES (HX_BYTES + BLDS_BYTES + 8*8*4)

DEV short8 cvt8(const float* s){
  float4 a = *(const float4*)s;
  float4 b = *(const float4*)(s+4);
  short8 r;
  r[0]=(short)f2b(a.x); r[1]=(short)f2b(a.y); r[2]=(short)f2b(a.z); r[3]=(short)f2b(a.w);
  r[4]=(short)f2b(b.x); r[5]=(short)f2b(b.y); r[6]=(short)f2b(b.z); r[7]=(short)f2b(b.w);
  return r;
}

// ============ GRU body: 512 thr = 8 waves, M=8 batches, N=768 gate rows ============
// wave w owns hidden cols [32w, 32w+32) = col-tiles {2w,2w+1}; gate N-tiles g*16+ct.
// B: K0..5 VGPR-resident (36 frags); K6,K7 (Whh cols 192..255) + K8 (Wih) in LDS.
template<int NSTEPS, bool IS_DEC>
DEV void gru_body(u16 (*hx)[RS], u16* Blds, float* psum,
                  const float* __restrict__ Whh, const float* __restrict__ Wih,
                  const float* __restrict__ bihP, const float* __restrict__ bhhP,
                  const float* __restrict__ X, const float* __restrict__ z0,
                  const float* __restrict__ lwrow, const float* __restrict__ lbp,
                  float* __restrict__ predp, int b0)
{
  const int tid = threadIdx.x;
  const int w = tid >> 6, lane = tid & 63;
  const int n = lane & 15, q = lane >> 4;

  // zero hx (rows 8..15 stay zero: A rows for the unused M half; x regions start zero)
  for (int idx = tid; idx < HX_BYTES/4; idx += 512) ((u32*)hx)[idx] = 0;
  __syncthreads();

  if (IS_DEC) {                      // h(0) = z (bf16)
    const int base = tid*4, m = base >> 8, c = base & 255;
    float4 v = *(const float4*)&z0[(b0+m)*256 + c];
    hx[m][c]   = f2b(v.x); hx[m][c+1] = f2b(v.y);
    hx[m][c+2] = f2b(v.z); hx[m][c+3] = f2b(v.w);
  } else {                           // h(0)=0 already; stage x(0) parity 0
    if (tid < 256) {
      const int m = tid >> 5, c = tid & 31;
      hx[m][256 + c] = f2b(X[(b0+m)*2048 + c]);
    }
  }

  // stage Blds: 48 ntiles x {K6,K7,K8} x 64 lanes, bf16-converted from fp32
  #pragma unroll
  for (int r = 0; r < 18; ++r) {
    const int tau = r*512 + tid;     // 0..9215
    const int nt = tau / 192, rem = tau - nt*192;
    const int kk = rem >> 6, l = rem & 63;
    const int nl = l & 15, ql = l >> 4;
    const int row = nt*16 + nl;
    const float* src = (kk < 2) ? (Whh + row*256 + (6+kk)*32 + ql*8)
                                : (Wih + row*32 + ql*8);
    *(short8*)&Blds[((nt*3 + kk)*64 + l)*8] = cvt8(src);
  }

  // resident B: K0..5 for wave's 6 N-tiles
  short8 Bres[36];
  #pragma unroll
  for (int i = 0; i < 2; ++i)
    #pragma unroll
    for (int g = 0; g < 3; ++g) {
      const int row = (g*16 + 2*w + i)*16 + n;
      #pragma unroll
      for (int k = 0; k < 6; ++k)
        Bres[(i*3+g)*6 + k] = cvt8(Whh + row*256 + k*32 + q*8);
    }

  float br[2], bz[2], bnx[2], bnh[2], lw[2];
  #pragma unroll
  for (int i = 0; i < 2; ++i) {
    const int col = (2*w + i)*16 + n;
    br[i]  = bihP[col]     + bhhP[col];
    bz[i]  = bihP[256+col] + bhhP[256+col];
    bnx[i] = bihP[512+col];
    bnh[i] = bhhP[512+col];
    lw[i]  = IS_DEC ? lwrow[col] : 0.f;
  }
  const float lb = IS_DEC ? lbp[0] : 0.f;
  __syncthreads();

  #pragma unroll 1
  for (int t = 0; t < NSTEPS; ++t) {
    // finalize pred(t-1) (psum written before last barrier)
    if (IS_DEC && t > 0 && tid < 8) {
      float s = lb;
      #pragma unroll
      for (int ww = 0; ww < 8; ++ww) s += psum[ww*8 + tid];
      predp[(b0 + tid)*54 + (t-1)] = s;
    }
    // A-fragments of [h(t-1) | x(t)]
    short8 af[9];
    #pragma unroll
    for (int k0 = 0; k0 < 8; ++k0)
      af[k0] = *(const short8*)&hx[n][k0*32 + q*8];
    af[8] = *(const short8*)&hx[n][256 + 32*(t & 1) + q*8];
    // stage x(t+1) into opposite parity (consumed only after next barrier)
    if (t+1 < NSTEPS && tid < 256) {
      const int m = tid >> 5, c = tid & 31;
      const float v = X[(b0+m)*2048 + ((IS_DEC ? (t+10) : (t+1)))*32 + c];
      hx[m][256 + 32*((t+1)&1) + c] = f2b(v);
    }

    float hnew[2][4];
    float part[4] = {0.f,0.f,0.f,0.f};
    #pragma unroll
    for (int i = 0; i < 2; ++i) {
      const int ntr =  0 + 2*w + i, ntz = 16 + 2*w + i, ntn = 32 + 2*w + i;
      f32x4 ar={0,0,0,0}, az={0,0,0,0}, anh={0,0,0,0}, anx={0,0,0,0};
      {
        short8 b6 = *(const short8*)&Blds[((ntr*3+0)*64+lane)*8];
        short8 b7 = *(const short8*)&Blds[((ntr*3+1)*64+lane)*8];
        short8 b8 = *(const short8*)&Blds[((ntr*3+2)*64+lane)*8];
        #pragma unroll
        for (int k = 0; k < 6; ++k)
          ar = __builtin_amdgcn_mfma_f32_16x16x32_bf16(af[k], Bres[(i*3+0)*6+k], ar, 0,0,0);
        ar = __builtin_amdgcn_mfma_f32_16x16x32_bf16(af[6], b6, ar, 0,0,0);
        ar = __builtin_amdgcn_mfma_f32_16x16x32_bf16(af[7], b7, ar, 0,0,0);
        ar = __builtin_amdgcn_mfma_f32_16x16x32_bf16(af[8], b8, ar, 0,0,0);
      }
      {
        short8 b6 = *(const short8*)&Blds[((ntz*3+0)*64+lane)*8];
        short8 b7 = *(const short8*)&Blds[((ntz*3+1)*64+lane)*8];
        short8 b8 = *(const short8*)&Blds[((ntz*3+2)*64+lane)*8];
        #pragma unroll
        for (int k = 0; k < 6; ++k)
          az = __builtin_amdgcn_mfma_f32_16x16x32_bf16(af[k], Bres[(i*3+1)*6+k], az, 0,0,0);
        az = __builtin_amdgcn_mfma_f32_16x16x32_bf16(af[6], b6, az, 0,0,0);
        az = __builtin_amdgcn_mfma_f32_16x16x32_bf16(af[7], b7, az, 0,0,0);
        az = __builtin_amdgcn_mfma_f32_16x16x32_bf16(af[8], b8, az, 0,0,0);
      }
      {
        short8 b6 = *(const short8*)&Blds[((ntn*3+0)*64+lane)*8];
        short8 b7 = *(const short8*)&Blds[((ntn*3+1)*64+lane)*8];
        short8 b8 = *(const short8*)&Blds[((ntn*3+2)*64+lane)*8];
        #pragma unroll
        for (int k = 0; k < 6; ++k)
          anh = __builtin_amdgcn_mfma_f32_16x16x32_bf16(af[k], Bres[(i*3+2)*6+k], anh, 0,0,0);
        anh = __builtin_amdgcn_mfma_f32_16x16x32_bf16(af[6], b6, anh, 0,0,0);
        anh = __builtin_amdgcn_mfma_f32_16x16x32_bf16(af[7], b7, anh, 0,0,0);
        anx = __builtin_amdgcn_mfma_f32_16x16x32_bf16(af[8], b8, anx, 0,0,0);
      }
      #pragma unroll
      for (int rr = 0; rr < 4; ++rr) {
        const int m = q*4 + rr;        // valid for q<2 (m<8); q>=2 computes discarded junk
        const float rg = sigm(ar[rr] + br[i]);
        const float zg = sigm(az[rr] + bz[i]);
        const float nv = tanh_(anx[rr] + bnx[i] + rg*(anh[rr] + bnh[i]));
        const float hold = b2f(hx[m][(2*w+i)*16 + n]);
        hnew[i][rr] = (1.f - zg)*nv + zg*hold;
        part[rr] += hnew[i][rr] * lw[i];
      }
    }
    if (IS_DEC) {                      // reduce over the 16 lanes of each q-group
      #pragma unroll
      for (int rr = 0; rr < 4; ++rr) {
        part[rr] += __shfl_xor(part[rr], 1, 64);
        part[rr] += __shfl_xor(part[rr], 2, 64);
        part[rr] += __shfl_xor(part[rr], 4, 64);
        part[rr] += __shfl_xor(part[rr], 8, 64);
      }
    }
    __syncthreads();                   // B1: all reads of h(t-1)/psum done
    if (q < 2) {
      #pragma unroll
      for (int i = 0; i < 2; ++i)
        #pragma unroll
        for (int rr = 0; rr < 4; ++rr)
          hx[q*4+rr][(2*w+i)*16 + n] = f2b(hnew[i][rr]);
      if (IS_DEC && n == 0)
        *(float4*)&psum[w*8 + q*4] = make_float4(part[0], part[1], part[2], part[3]);
    }
    __syncthreads();                   // B2: h(t) + psum complete
  }
  if (IS_DEC && tid < 8) {
    float s = lb;
    #pragma unroll
    for (int ww = 0; ww < 8; ++ww) s += psum[ww*8 + tid];
    predp[(b0 + tid)*54 + (NSTEPS-1)] = s;
  }
}

// ===================== encoder + latent (fused) =====================
__global__ __launch_bounds__(512, 2) void enc_lat(
    const float* __restrict__ Whh, const float* __restrict__ Wih,
    const float* __restrict__ bih, const float* __restrict__ bhh,
    const float* __restrict__ X,
    const float* __restrict__ Wmu, const float* __restrict__ bmu,
    const float* __restrict__ Wsd, const float* __restrict__ bsd,
    const float* __restrict__ eps,
    float* __restrict__ z, float* __restrict__ out_lv, float* __restrict__ out_mu)
{
  extern __shared__ char smem[];
  u16 (*hx)[RS] = (u16 (*)[RS])smem;
  u16* Blds = (u16*)(smem + HX_BYTES);
  float* psum = (float*)(smem + HX_BYTES + BLDS_BYTES);
  const int b0 = blockIdx.y * 8;
  gru_body<10, false>(hx, Blds, psum, Whh, Wih, bih, bhh, X,
                      nullptr, nullptr, nullptr, nullptr, b0);
  // ---- latent: mu/lv/z for batches b0..b0+7 from bf16 h in hx rows 0..7
  const int tid = threadIdx.x;
  const int j = tid & 255, half = tid >> 8;
  float am[4] = {0,0,0,0}, as[4] = {0,0,0,0};
  const float* wmrow = Wmu + j*256;
  const float* wsrow = Wsd + j*256;
  #pragma unroll 4
  for (int c0 = 0; c0 < 256; c0 += 8) {
    float4 wm0 = *(const float4*)&wmrow[c0];
    float4 wm1 = *(const float4*)&wmrow[c0+4];
    float4 ws0 = *(const float4*)&wsrow[c0];
    float4 ws1 = *(const float4*)&wsrow[c0+4];
    #pragma unroll
    for (int mm = 0; mm < 4; ++mm) {
      const u16* hp = &hx[half*4 + mm][c0];
      float4 h0 = make_float4(b2f(hp[0]), b2f(hp[1]), b2f(hp[2]), b2f(hp[3]));
      float4 h1 = make_float4(b2f(hp[4]), b2f(hp[5]), b2f(hp[6]), b2f(hp[7]));
      am[mm] += dot4(wm0, h0) + dot4(wm1, h1);
      as[mm] += dot4(ws0, h0) + dot4(ws1, h1);
    }
  }
  #pragma unroll
  for (int mm = 0; mm < 4; ++mm) {
    const int b = b0 + half*4 + mm;
    const float mu = am[mm] + bmu[j];
    const float lv = as[mm] + bsd[j];
    const float zv = mu + __expf(0.5f*lv) * eps[b*256 + j];
    z[b*256 + j]      = zv;
    out_lv[b*256 + j] = lv;
    out_mu[b*256 + j] = mu;
  }
}

// ===================== decoder =====================
// grid (32 series, 8 batch-slices): linear id = p + 32*s -> XCD = p%8 (L2 locality at startup)
__global__ __launch_bounds__(512, 2) void dec_mfma(
    const float* __restrict__ Whh, const float* __restrict__ Wih,
    const float* __restrict__ bih, const float* __restrict__ bhh,
    const float* __restrict__ X, const float* __restrict__ z,
    const float* __restrict__ lin_w, const float* __restrict__ lin_b,
    float* __restrict__ pred)
{
  extern __shared__ char smem[];
  u16 (*hx)[RS] = (u16 (*)[RS])smem;
  u16* Blds = (u16*)(smem + HX_BYTES);
  float* psum = (float*)(smem + HX_BYTES + BLDS_BYTES);
  const int p = blockIdx.x;
  const int b0 = blockIdx.y * 8;
  gru_body<54, true>(hx, Blds, psum,
                     Whh + p*196608, Wih + p*24576,
                     bih + p*768, bhh + p*768, X, z,
                     lin_w + p*256, lin_b + p, pred + p*3456, b0);
}

extern "C" void kernel_launch(void* const* d_in, const int* in_sizes, int n_in,
                              void* d_out, int out_size, void* d_ws, size_t ws_size,
                              hipStream_t stream) {
  const float* X        = (const float*)d_in[0];
  const float* eps      = (const float*)d_in[1];
  const float* Wih_enc  = (const float*)d_in[2];
  const float* Whh_enc  = (const float*)d_in[3];
  const float* bih_enc  = (const float*)d_in[4];
  const float* bhh_enc  = (const float*)d_in[5];
  const float* fc_mu_w  = (const float*)d_in[6];
  const float* fc_mu_b  = (const float*)d_in[7];
  const float* fc_std_w = (const float*)d_in[8];
  const float* fc_std_b = (const float*)d_in[9];
  const float* Wih_dec  = (const float*)d_in[10];
  const float* Whh_dec  = (const float*)d_in[11];
  const float* bih_dec  = (const float*)d_in[12];
  const float* bhh_dec  = (const float*)d_in[13];
  const float* lin_w    = (const float*)d_in[14];
  const float* lin_b    = (const float*)d_in[15];

  float* out    = (float*)d_out;
  float* pred   = out;              // [32][64][54][1] = 110592
  float* out_lv = out + 110592;     // [1][64][256]
  float* out_mu = out + 126976;     // [1][64][256]

  float* z = (float*)d_ws;          // [64][256] fp32

  static bool attr_done = false;
  (void)hipFuncSetAttribute((const void*)enc_lat,
      hipFuncAttributeMaxDynamicSharedMemorySize, SMEM_BYTES);
  (void)hipFuncSetAttribute((const void*)dec_mfma,
      hipFuncAttributeMaxDynamicSharedMemorySize, SMEM_BYTES);
  (void)attr_done;

  enc_lat<<<dim3(1, 8), 512, SMEM_BYTES, stream>>>(
      Whh_enc, Wih_enc, bih_enc, bhh_enc, X,
      fc_mu_w, fc_mu_b, fc_std_w, fc_std_b, eps, z, out_lv, out_mu);
  dec_mfma<<<dim3(32, 8), 512, SMEM_BYTES, stream>>>(
      Whh_dec, Wih_dec, bih_dec, bhh_dec, X, z, lin_w, lin_b, pred);
}

// Round 6
// 355.894 us; speedup vs baseline: 6.3327x; 1.1151x over previous
//
#include <hip/hip_runtime.h>

typedef unsigned int u32;
typedef unsigned short u16;
typedef __attribute__((ext_vector_type(8))) short short8;
typedef __attribute__((ext_vector_type(4))) float f32x4;

#define DEV static __device__ __forceinline__

DEV float b2f(u16 v){ union{u32 u; float f;} c; c.u = ((u32)v) << 16; return c.f; }
DEV u16 f2b(float f){ union{float ff; u32 u;} c; c.ff = f; return (u16)((c.u + 0x7fffu + ((c.u >> 16) & 1u)) >> 16); }
DEV float sigm(float x){ return 1.f/(1.f + __expf(-x)); }
DEV float tanh_(float x){ float e = __expf(-2.f*x); return (1.f-e)/(1.f+e); }

// dims: B=64, T=64, P=32, H=256, 3H=768.
// LDS (dynamic): Blds 48nt x {K6,K7,K8} x 1KB (147456 B) | hxA 8 k0-frags x 64 lanes x 8 u16
// (8192 B, A-fragment-packed h) | xA 2 parity x 512 u16 (2048 B) | psum 64 f32 (256 B)
#define BLDS_U16  (48*3*64*8)
#define HXA_U16   (8*64*8)
#define XA_U16    (2*64*8)
#define SMEM_BYTES ((BLDS_U16 + HXA_U16 + XA_U16)*2 + 64*4)

// element (m row, c col) -> u16 index in frag-packed hxA
DEV int hxi(int m, int c){ return (((c>>5)<<6) + m + (((c>>3)&3)<<4))*8 + (c&7); }

DEV short8 cvt8(const float* s){
  float4 a = *(const float4*)s;
  float4 b = *(const float4*)(s+4);
  short8 r;
  r[0]=(short)f2b(a.x); r[1]=(short)f2b(a.y); r[2]=(short)f2b(a.z); r[3]=(short)f2b(a.w);
  r[4]=(short)f2b(b.x); r[5]=(short)f2b(b.y); r[6]=(short)f2b(b.z); r[7]=(short)f2b(b.w);
  return r;
}

// ============ GRU body: 512 thr = 8 waves, M=8 batches, N=768 gate rows ============
// wave w owns hidden cols [32w, 32w+32) = col-tiles {2w, 2w+1}.
// B: K0..5 VGPR-resident (36 frags, asm-pinned); K6,K7 (Whh) + K8 (Wih) in LDS.
template<int NSTEPS, bool IS_DEC>
DEV void gru_body(u16* hxA, u16* xA, u16* Blds, float* psum,
                  const float* __restrict__ Whh, const float* __restrict__ Wih,
                  const float* __restrict__ bihP, const float* __restrict__ bhhP,
                  const float* __restrict__ X, const float* __restrict__ z0,
                  const float* __restrict__ lwrow, const float* __restrict__ lbp,
                  float* __restrict__ predp, int b0)
{
  const int tid = threadIdx.x;
  const int w = tid >> 6, lane = tid & 63;
  const int n = lane & 15, q = lane >> 4;

  // zero hxA + xA (A rows 8..15 stay zero forever; x parity-0 zero for dec t=0)
  for (int idx = tid; idx < (HXA_U16 + XA_U16)/2; idx += 512)
    ((u32*)hxA)[idx] = 0;          // hxA and xA are contiguous (xA = hxA + HXA_U16)
  __syncthreads();

  if (IS_DEC) {                    // h(0) = z (bf16, frag-packed)
    const int m = tid >> 6, c0 = (tid*4) & 255;
    float4 v = *(const float4*)&z0[(b0+m)*256 + c0];
    const int base = hxi(m, c0);   // c0 % 4 == 0 -> 4 contiguous u16
    hxA[base]   = f2b(v.x); hxA[base+1] = f2b(v.y);
    hxA[base+2] = f2b(v.z); hxA[base+3] = f2b(v.w);
  } else {                         // stage x(0) into parity 0
    if (tid < 256) {
      const int m = tid >> 5, c = tid & 31;
      xA[(m + 16*(c>>3))*8 + (c&7)] = f2b(X[(b0+m)*2048 + c]);
    }
  }

  // stage Blds: 48 ntiles x {K6,K7,K8} x 64 lanes, bf16-converted from fp32
  #pragma unroll
  for (int r = 0; r < 18; ++r) {
    const int tau = r*512 + tid;   // 0..9215
    const int nt = tau / 192, rem = tau - nt*192;
    const int kk = rem >> 6, l = rem & 63;
    const int nl = l & 15, ql = l >> 4;
    const int row = nt*16 + nl;
    const float* src = (kk < 2) ? (Whh + row*256 + (6+kk)*32 + ql*8)
                                : (Wih + row*32 + ql*8);
    *(short8*)&Blds[((nt*3 + kk)*64 + l)*8] = cvt8(src);
  }

  // resident B: K0..5 for wave's 6 N-tiles; asm-pin to defeat rematerialization
  short8 Bres[36];
  #pragma unroll
  for (int i = 0; i < 2; ++i)
    #pragma unroll
    for (int g = 0; g < 3; ++g) {
      const int row = (g*16 + 2*w + i)*16 + n;
      #pragma unroll
      for (int k = 0; k < 6; ++k)
        Bres[(i*3+g)*6 + k] = cvt8(Whh + row*256 + k*32 + q*8);
    }
  #pragma unroll
  for (int r = 0; r < 36; ++r)
    asm volatile("" : "+v"(Bres[r]));

  float br[2], bz[2], bnx[2], bnh[2], lw[2];
  #pragma unroll
  for (int i = 0; i < 2; ++i) {
    const int col = (2*w + i)*16 + n;
    br[i]  = bihP[col]     + bhhP[col];
    bz[i]  = bihP[256+col] + bhhP[256+col];
    bnx[i] = bihP[512+col];
    bnh[i] = bhhP[512+col];
    lw[i]  = IS_DEC ? lwrow[col] : 0.f;
  }
  const float lb = IS_DEC ? lbp[0] : 0.f;
  __syncthreads();

  #pragma unroll 1
  for (int t = 0; t < NSTEPS; ++t) {
    // finalize pred(t-1) (psum written before last barrier)
    if (IS_DEC && t > 0 && tid < 8) {
      float s = lb;
      #pragma unroll
      for (int ww = 0; ww < 8; ++ww) s += psum[ww*8 + tid];
      predp[(b0 + tid)*54 + (t-1)] = s;
    }
    // A-fragments of [h(t-1) | x(t)] — all reads at addr lane*16 (conflict-free)
    short8 af[9];
    #pragma unroll
    for (int k0 = 0; k0 < 8; ++k0)
      af[k0] = *(const short8*)&hxA[(k0*64 + lane)*8];
    af[8] = *(const short8*)&xA[(t&1)*512 + lane*8];
    // stage x(t+1) into opposite parity (consumed only after next barrier pair)
    if (t+1 < NSTEPS && tid < 256) {
      const int m = tid >> 5, c = tid & 31;
      const float v = X[(b0+m)*2048 + ((IS_DEC ? (t+10) : (t+1)))*32 + c];
      xA[((t+1)&1)*512 + (m + 16*(c>>3))*8 + (c&7)] = f2b(v);
    }

    float hnew[2][4];
    float part[4] = {0.f,0.f,0.f,0.f};
    #pragma unroll
    for (int i = 0; i < 2; ++i) {
      const int ntr =  0 + 2*w + i, ntz = 16 + 2*w + i, ntn = 32 + 2*w + i;
      f32x4 ar={0,0,0,0}, az={0,0,0,0}, anh={0,0,0,0}, anx={0,0,0,0};
      {
        short8 b6 = *(const short8*)&Blds[((ntr*3+0)*64+lane)*8];
        short8 b7 = *(const short8*)&Blds[((ntr*3+1)*64+lane)*8];
        short8 b8 = *(const short8*)&Blds[((ntr*3+2)*64+lane)*8];
        #pragma unroll
        for (int k = 0; k < 6; ++k)
          ar = __builtin_amdgcn_mfma_f32_16x16x32_bf16(af[k], Bres[(i*3+0)*6+k], ar, 0,0,0);
        ar = __builtin_amdgcn_mfma_f32_16x16x32_bf16(af[6], b6, ar, 0,0,0);
        ar = __builtin_amdgcn_mfma_f32_16x16x32_bf16(af[7], b7, ar, 0,0,0);
        ar = __builtin_amdgcn_mfma_f32_16x16x32_bf16(af[8], b8, ar, 0,0,0);
      }
      {
        short8 b6 = *(const short8*)&Blds[((ntz*3+0)*64+lane)*8];
        short8 b7 = *(const short8*)&Blds[((ntz*3+1)*64+lane)*8];
        short8 b8 = *(const short8*)&Blds[((ntz*3+2)*64+lane)*8];
        #pragma unroll
        for (int k = 0; k < 6; ++k)
          az = __builtin_amdgcn_mfma_f32_16x16x32_bf16(af[k], Bres[(i*3+1)*6+k], az, 0,0,0);
        az = __builtin_amdgcn_mfma_f32_16x16x32_bf16(af[6], b6, az, 0,0,0);
        az = __builtin_amdgcn_mfma_f32_16x16x32_bf16(af[7], b7, az, 0,0,0);
        az = __builtin_amdgcn_mfma_f32_16x16x32_bf16(af[8], b8, az, 0,0,0);
      }
      {
        short8 b6 = *(const short8*)&Blds[((ntn*3+0)*64+lane)*8];
        short8 b7 = *(const short8*)&Blds[((ntn*3+1)*64+lane)*8];
        short8 b8 = *(const short8*)&Blds[((ntn*3+2)*64+lane)*8];
        #pragma unroll
        for (int k = 0; k < 6; ++k)
          anh = __builtin_amdgcn_mfma_f32_16x16x32_bf16(af[k], Bres[(i*3+2)*6+k], anh, 0,0,0);
        anh = __builtin_amdgcn_mfma_f32_16x16x32_bf16(af[6], b6, anh, 0,0,0);
        anh = __builtin_amdgcn_mfma_f32_16x16x32_bf16(af[7], b7, anh, 0,0,0);
        anx = __builtin_amdgcn_mfma_f32_16x16x32_bf16(af[8], b8, anx, 0,0,0);
      }
      const int col = (2*w + i)*16 + n;
      #pragma unroll
      for (int rr = 0; rr < 4; ++rr) {
        const int m = q*4 + rr;      // valid for q<2; q>=2 computes discarded junk
        const float rg = sigm(ar[rr] + br[i]);
        const float zg = sigm(az[rr] + bz[i]);
        const float nv = tanh_(anx[rr] + bnx[i] + rg*(anh[rr] + bnh[i]));
        const float hold = b2f(hxA[hxi(m, col)]);
        hnew[i][rr] = (1.f - zg)*nv + zg*hold;
        part[rr] += hnew[i][rr] * lw[i];
      }
    }
    if (IS_DEC) {                    // reduce over the 16 lanes of each q-group
      #pragma unroll
      for (int rr = 0; rr < 4; ++rr) {
        part[rr] += __shfl_xor(part[rr], 1, 64);
        part[rr] += __shfl_xor(part[rr], 2, 64);
        part[rr] += __shfl_xor(part[rr], 4, 64);
        part[rr] += __shfl_xor(part[rr], 8, 64);
      }
    }
    __syncthreads();                 // B1: all reads of h(t-1)/psum done
    if (q < 2) {
      #pragma unroll
      for (int i = 0; i < 2; ++i) {
        const int col = (2*w + i)*16 + n;
        #pragma unroll
        for (int rr = 0; rr < 4; ++rr)
          hxA[hxi(q*4 + rr, col)] = f2b(hnew[i][rr]);
      }
      if (IS_DEC && n == 0)
        *(float4*)&psum[w*8 + q*4] = make_float4(part[0], part[1], part[2], part[3]);
    }
    __syncthreads();                 // B2: h(t) + psum complete
  }
  if (IS_DEC && tid < 8) {
    float s = lb;
    #pragma unroll
    for (int ww = 0; ww < 8; ++ww) s += psum[ww*8 + tid];
    predp[(b0 + tid)*54 + (NSTEPS-1)] = s;
  }
}

// ===================== encoder + latent (fused) =====================
__global__ __launch_bounds__(512, 2) void enc_lat(
    const float* __restrict__ Whh, const float* __restrict__ Wih,
    const float* __restrict__ bih, const float* __restrict__ bhh,
    const float* __restrict__ X,
    const float* __restrict__ Wmu, const float* __restrict__ bmu,
    const float* __restrict__ Wsd, const float* __restrict__ bsd,
    const float* __restrict__ eps,
    float* __restrict__ z, float* __restrict__ out_lv, float* __restrict__ out_mu)
{
  extern __shared__ char smem[];
  u16* Blds = (u16*)smem;
  u16* hxA  = (u16*)(smem + BLDS_U16*2);
  u16* xA   = hxA + HXA_U16;
  float* psum = (float*)(smem + (BLDS_U16 + HXA_U16 + XA_U16)*2);
  const int b0 = blockIdx.y * 8;
  gru_body<10, false>(hxA, xA, Blds, psum, Whh, Wih, bih, bhh, X,
                      nullptr, nullptr, nullptr, nullptr, b0);
  __syncthreads();
  // ---- latent: mu/lv/z for batches b0..b0+7 from bf16 h in hxA rows 0..7
  const int tid = threadIdx.x;
  const int j = tid & 255, half = tid >> 8;
  float am[4] = {0,0,0,0}, as[4] = {0,0,0,0};
  const float* wmrow = Wmu + j*256;
  const float* wsrow = Wsd + j*256;
  #pragma unroll 2
  for (int c0 = 0; c0 < 256; c0 += 8) {
    float4 wm0 = *(const float4*)&wmrow[c0];
    float4 wm1 = *(const float4*)&wmrow[c0+4];
    float4 ws0 = *(const float4*)&wsrow[c0];
    float4 ws1 = *(const float4*)&wsrow[c0+4];
    #pragma unroll
    for (int mm = 0; mm < 4; ++mm) {
      const int m = half*4 + mm;
      const u16* hp = &hxA[hxi(m, c0)];      // c0 % 8 == 0 -> 8 contiguous u16
      float h0x=b2f(hp[0]), h0y=b2f(hp[1]), h0z=b2f(hp[2]), h0w=b2f(hp[3]);
      float h1x=b2f(hp[4]), h1y=b2f(hp[5]), h1z=b2f(hp[6]), h1w=b2f(hp[7]);
      am[mm] += wm0.x*h0x + wm0.y*h0y + wm0.z*h0z + wm0.w*h0w
              + wm1.x*h1x + wm1.y*h1y + wm1.z*h1z + wm1.w*h1w;
      as[mm] += ws0.x*h0x + ws0.y*h0y + ws0.z*h0z + ws0.w*h0w
              + ws1.x*h1x + ws1.y*h1y + ws1.z*h1z + ws1.w*h1w;
    }
  }
  #pragma unroll
  for (int mm = 0; mm < 4; ++mm) {
    const int b = b0 + half*4 + mm;
    const float mu = am[mm] + bmu[j];
    const float lv = as[mm] + bsd[j];
    const float zv = mu + __expf(0.5f*lv) * eps[b*256 + j];
    z[b*256 + j]      = zv;
    out_lv[b*256 + j] = lv;
    out_mu[b*256 + j] = mu;
  }
}

// ===================== decoder =====================
// grid (32 series, 8 batch-slices): linear id = p + 32*s -> XCD = p%8 (L2 locality)
__global__ __launch_bounds__(512, 2) void dec_mfma(
    const float* __restrict__ Whh, const float* __restrict__ Wih,
    const float* __restrict__ bih, const float* __restrict__ bhh,
    const float* __restrict__ X, const float* __restrict__ z,
    const float* __restrict__ lin_w, const float* __restrict__ lin_b,
    float* __restrict__ pred)
{
  extern __shared__ char smem[];
  u16* Blds = (u16*)smem;
  u16* hxA  = (u16*)(smem + BLDS_U16*2);
  u16* xA   = hxA + HXA_U16;
  float* psum = (float*)(smem + (BLDS_U16 + HXA_U16 + XA_U16)*2);
  const int p = blockIdx.x;
  const int b0 = blockIdx.y * 8;
  gru_body<54, true>(hxA, xA, Blds, psum,
                     Whh + p*196608, Wih + p*24576,
                     bih + p*768, bhh + p*768, X, z,
                     lin_w + p*256, lin_b + p, pred + p*3456, b0);
}

extern "C" void kernel_launch(void* const* d_in, const int* in_sizes, int n_in,
                              void* d_out, int out_size, void* d_ws, size_t ws_size,
                              hipStream_t stream) {
  const float* X        = (const float*)d_in[0];
  const float* eps      = (const float*)d_in[1];
  const float* Wih_enc  = (const float*)d_in[2];
  const float* Whh_enc  = (const float*)d_in[3];
  const float* bih_enc  = (const float*)d_in[4];
  const float* bhh_enc  = (const float*)d_in[5];
  const float* fc_mu_w  = (const float*)d_in[6];
  const float* fc_mu_b  = (const float*)d_in[7];
  const float* fc_std_w = (const float*)d_in[8];
  const float* fc_std_b = (const float*)d_in[9];
  const float* Wih_dec  = (const float*)d_in[10];
  const float* Whh_dec  = (const float*)d_in[11];
  const float* bih_dec  = (const float*)d_in[12];
  const float* bhh_dec  = (const float*)d_in[13];
  const float* lin_w    = (const float*)d_in[14];
  const float* lin_b    = (const float*)d_in[15];

  float* out    = (float*)d_out;
  float* pred   = out;              // [32][64][54][1] = 110592
  float* out_lv = out + 110592;     // [1][64][256]
  float* out_mu = out + 126976;     // [1][64][256]

  float* z = (float*)d_ws;          // [64][256] fp32

  (void)hipFuncSetAttribute((const void*)enc_lat,
      hipFuncAttributeMaxDynamicSharedMemorySize, SMEM_BYTES);
  (void)hipFuncSetAttribute((const void*)dec_mfma,
      hipFuncAttributeMaxDynamicSharedMemorySize, SMEM_BYTES);

  enc_lat<<<dim3(1, 8), 512, SMEM_BYTES, stream>>>(
      Whh_enc, Wih_enc, bih_enc, bhh_enc, X,
      fc_mu_w, fc_mu_b, fc_std_w, fc_std_b, eps, z, out_lv, out_mu);
  dec_mfma<<<dim3(32, 8), 512, SMEM_BYTES, stream>>>(
      Whh_dec, Wih_dec, bih_dec, bhh_dec, X, z, lin_w, lin_b, pred);
}

// Round 7
// 327.552 us; speedup vs baseline: 6.8806x; 1.0865x over previous
//
#include <hip/hip_runtime.h>

typedef unsigned int u32;
typedef unsigned short u16;
typedef __attribute__((ext_vector_type(8))) short short8;
typedef __attribute__((ext_vector_type(4))) float f32x4;

#define DEV static __device__ __forceinline__

DEV float b2f(u16 v){ union{u32 u; float f;} c; c.u = ((u32)v) << 16; return c.f; }
DEV u16 f2b(float f){ union{float ff; u32 u;} c; c.ff = f; return (u16)((c.u + 0x7fffu + ((c.u >> 16) & 1u)) >> 16); }
DEV float sigm(float x){ return 1.f/(1.f + __expf(-x)); }
DEV float tanh_(float x){ float e = __expf(-2.f*x); return (1.f-e)/(1.f+e); }

// dims: B=64, T=64, P=32, H=256, 3H=768.
// Packed B in ws: per series ps: 48 N-tiles x 9 K-tiles x 64 lanes x 8 bf16.
#define SER_STRIDE 221184   // u16 per series = 48*9*64*8

// LDS: Blds (K6,K7,K8 frags: 48nt x 3 x 1KB) | hxA (8 k0-frags x 64 x 8 u16)
//      | xA (2 parity x 512 u16) | lwfc (8 k0 x 5 rows x 8 u16; row 4 = zeros)
#define BLDS_U16 (48*3*64*8)
#define HXA_U16  (8*64*8)
#define XA_U16   (2*64*8)
#define LWF_U16  (8*5*8)
#define SMEM_BYTES ((BLDS_U16 + HXA_U16 + XA_U16 + LWF_U16)*2)

// element (m row, c col) -> u16 index in frag-packed hxA
DEV int hxi(int m, int c){ return (((c>>5)<<6) + m + (((c>>3)&3)<<4))*8 + (c&7); }

// ===================== fragment pack (fp32 -> bf16 frags, once) =====================
__global__ __launch_bounds__(64) void pack_kernel(
    const float* __restrict__ WihD, const float* __restrict__ WhhD,
    const float* __restrict__ WihE, const float* __restrict__ WhhE,
    u16* __restrict__ wsB)
{
  const int ps = blockIdx.y;           // 0..31 dec series, 32 = encoder
  const int f  = blockIdx.x;           // n0*9 + k, 0..431
  const int n0 = f / 9, k = f - n0*9;
  const int lane = threadIdx.x;
  const int n = lane & 15, q = lane >> 4;
  const int row = n0*16 + n;
  const float* Whh = (ps < 32) ? WhhD + ps*196608 : WhhE;
  const float* Wih = (ps < 32) ? WihD + ps*24576  : WihE;
  const float* src = (k < 8) ? (Whh + row*256 + k*32 + q*8) : (Wih + row*32 + q*8);
  u32 wd[4];
  #pragma unroll
  for (int j = 0; j < 4; ++j) {
    u16 lo = f2b(src[2*j]);
    u16 hi = f2b(src[2*j+1]);
    wd[j] = (u32)lo | ((u32)hi << 16);
  }
  uint4* dst = (uint4*)(wsB + (((size_t)ps*432 + f)*64 + lane)*8);
  *dst = make_uint4(wd[0], wd[1], wd[2], wd[3]);
}

// ============ GRU body: 512 thr = 8 waves, M=8 batches, N=768 gate rows ============
// wave w owns hidden cols [32w, 32w+32) = col-tiles {2w, 2w+1}.
// B: K0..5 VGPR-resident (36 frags, pure packed loads + asm pin); K6..8 in LDS.
// lin-projection: wave 0 runs 8 extra MFMAs on af (h(t-1)) -> pred(t-1).
template<int NSTEPS, bool IS_DEC>
DEV void gru_body(u16* hxA, u16* xA, u16* Blds, u16* lwfc,
                  const u16* __restrict__ Bp,
                  const float* __restrict__ bihP, const float* __restrict__ bhhP,
                  const float* __restrict__ X, const float* __restrict__ z0,
                  const float* __restrict__ lwp, const float* __restrict__ lbp,
                  float* __restrict__ predp, int b0)
{
  const int tid = threadIdx.x;
  const int w = tid >> 6, lane = tid & 63;
  const int n = lane & 15, q = lane >> 4;

  // zero hxA + xA (contiguous); A rows 8..15 stay zero forever
  for (int idx = tid; idx < (HXA_U16 + XA_U16)/2; idx += 512)
    ((u32*)hxA)[idx] = 0;
  __syncthreads();

  if (IS_DEC) {                    // h(0) = z (bf16, frag-packed)
    const int m = tid >> 6, c0 = (tid*4) & 255;
    float4 v = *(const float4*)&z0[(b0+m)*256 + c0];
    const int base = hxi(m, c0);   // c0 % 4 == 0 -> 4 contiguous u16
    hxA[base]   = f2b(v.x); hxA[base+1] = f2b(v.y);
    hxA[base+2] = f2b(v.z); hxA[base+3] = f2b(v.w);
  } else {                         // stage x(0) into parity 0
    if (tid < 256) {
      const int m = tid >> 5, c = tid & 31;
      xA[(m + 16*(c>>3))*8 + (c&7)] = f2b(X[(b0+m)*2048 + c]);
    }
  }

  // stage lw fragment rows (dec only): row r<4 = lw[k0*32+r*8+j], row 4 = zeros
  if (IS_DEC && tid < 320) {
    const int k0 = tid / 40, rem = tid - k0*40;
    const int r = rem >> 3, j = rem & 7;
    lwfc[(k0*5 + r)*8 + j] = (r < 4) ? f2b(lwp[k0*32 + r*8 + j]) : (u16)0;
  }

  // stage Blds: K6,K7,K8 frags for all 48 ntiles — pure uint4 copies
  #pragma unroll
  for (int r = 0; r < 18; ++r) {
    const int g = r*512 + tid;     // 0..9215 uint4s
    const int frag = g >> 6, e = g & 63;
    const int nt = frag / 3, kk = frag - nt*3;
    ((uint4*)Blds)[g] = ((const uint4*)Bp)[((size_t)nt*9 + 6 + kk)*64 + e];
  }

  // resident B: K0..5 for wave's 6 N-tiles — pure short8 loads + pin
  short8 Bres[36];
  #pragma unroll
  for (int i = 0; i < 2; ++i)
    #pragma unroll
    for (int g = 0; g < 3; ++g)
      #pragma unroll
      for (int k = 0; k < 6; ++k)
        Bres[(i*3+g)*6 + k] =
          *(const short8*)(Bp + (((size_t)(g*16 + 2*w + i)*9 + k)*64 + lane)*8);
  #pragma unroll
  for (int r = 0; r < 36; ++r)
    asm volatile("" : "+v"(Bres[r]));

  float br[2], bz[2], bnx[2], bnh[2];
  #pragma unroll
  for (int i = 0; i < 2; ++i) {
    const int col = (2*w + i)*16 + n;
    br[i]  = bihP[col]     + bhhP[col];
    bz[i]  = bihP[256+col] + bhhP[256+col];
    bnx[i] = bihP[512+col];
    bnh[i] = bhhP[512+col];
  }
  const float lb = IS_DEC ? lbp[0] : 0.f;
  __syncthreads();

  #pragma unroll 1
  for (int t = 0; t < NSTEPS; ++t) {
    // A-fragments of [h(t-1) | x(t)] — all reads at addr lane*16 (conflict-free)
    short8 af[9];
    #pragma unroll
    for (int k0 = 0; k0 < 8; ++k0)
      af[k0] = *(const short8*)&hxA[(k0*64 + lane)*8];
    af[8] = *(const short8*)&xA[(t&1)*512 + lane*8];

    // lin-projection of h(t-1) -> pred(t-1) via MFMA (wave 0 only, t>=1)
    if (IS_DEC && w == 0 && t > 0) {
      f32x4 lp = {0,0,0,0};
      #pragma unroll
      for (int k0 = 0; k0 < 8; ++k0) {
        const short8 lf = *(const short8*)&lwfc[(k0*5 + ((n==0) ? q : 4))*8];
        lp = __builtin_amdgcn_mfma_f32_16x16x32_bf16(af[k0], lf, lp, 0,0,0);
      }
      if (n == 0 && q < 2) {
        #pragma unroll
        for (int rr = 0; rr < 4; ++rr)
          predp[(b0 + q*4 + rr)*54 + (t-1)] = lp[rr] + lb;
      }
    }

    // stage x(t+1) into opposite parity (consumed only after next barrier pair)
    if (t+1 < NSTEPS && tid < 256) {
      const int m = tid >> 5, c = tid & 31;
      const float v = X[(b0+m)*2048 + ((IS_DEC ? (t+10) : (t+1)))*32 + c];
      xA[((t+1)&1)*512 + (m + 16*(c>>3))*8 + (c&7)] = f2b(v);
    }

    float hnew[2][4];
    #pragma unroll
    for (int i = 0; i < 2; ++i) {
      const int ntr =  0 + 2*w + i, ntz = 16 + 2*w + i, ntn = 32 + 2*w + i;
      f32x4 ar={0,0,0,0}, az={0,0,0,0}, anh={0,0,0,0}, anx={0,0,0,0};
      {
        short8 b6 = *(const short8*)&Blds[((ntr*3+0)*64+lane)*8];
        short8 b7 = *(const short8*)&Blds[((ntr*3+1)*64+lane)*8];
        short8 b8 = *(const short8*)&Blds[((ntr*3+2)*64+lane)*8];
        #pragma unroll
        for (int k = 0; k < 6; ++k)
          ar = __builtin_amdgcn_mfma_f32_16x16x32_bf16(af[k], Bres[(i*3+0)*6+k], ar, 0,0,0);
        ar = __builtin_amdgcn_mfma_f32_16x16x32_bf16(af[6], b6, ar, 0,0,0);
        ar = __builtin_amdgcn_mfma_f32_16x16x32_bf16(af[7], b7, ar, 0,0,0);
        ar = __builtin_amdgcn_mfma_f32_16x16x32_bf16(af[8], b8, ar, 0,0,0);
      }
      {
        short8 b6 = *(const short8*)&Blds[((ntz*3+0)*64+lane)*8];
        short8 b7 = *(const short8*)&Blds[((ntz*3+1)*64+lane)*8];
        short8 b8 = *(const short8*)&Blds[((ntz*3+2)*64+lane)*8];
        #pragma unroll
        for (int k = 0; k < 6; ++k)
          az = __builtin_amdgcn_mfma_f32_16x16x32_bf16(af[k], Bres[(i*3+1)*6+k], az, 0,0,0);
        az = __builtin_amdgcn_mfma_f32_16x16x32_bf16(af[6], b6, az, 0,0,0);
        az = __builtin_amdgcn_mfma_f32_16x16x32_bf16(af[7], b7, az, 0,0,0);
        az = __builtin_amdgcn_mfma_f32_16x16x32_bf16(af[8], b8, az, 0,0,0);
      }
      {
        short8 b6 = *(const short8*)&Blds[((ntn*3+0)*64+lane)*8];
        short8 b7 = *(const short8*)&Blds[((ntn*3+1)*64+lane)*8];
        short8 b8 = *(const short8*)&Blds[((ntn*3+2)*64+lane)*8];
        #pragma unroll
        for (int k = 0; k < 6; ++k)
          anh = __builtin_amdgcn_mfma_f32_16x16x32_bf16(af[k], Bres[(i*3+2)*6+k], anh, 0,0,0);
        anh = __builtin_amdgcn_mfma_f32_16x16x32_bf16(af[6], b6, anh, 0,0,0);
        anh = __builtin_amdgcn_mfma_f32_16x16x32_bf16(af[7], b7, anh, 0,0,0);
        anx = __builtin_amdgcn_mfma_f32_16x16x32_bf16(af[8], b8, anx, 0,0,0);
      }
      const int col = (2*w + i)*16 + n;
      #pragma unroll
      for (int rr = 0; rr < 4; ++rr) {
        const int m = q*4 + rr;      // valid for q<2; q>=2 computes discarded junk
        const float rg = sigm(ar[rr] + br[i]);
        const float zg = sigm(az[rr] + bz[i]);
        const float nv = tanh_(anx[rr] + bnx[i] + rg*(anh[rr] + bnh[i]));
        const float hold = b2f(hxA[hxi(m, col)]);
        hnew[i][rr] = (1.f - zg)*nv + zg*hold;
      }
    }
    __syncthreads();                 // B1: all reads of h(t-1) done
    if (q < 2) {
      #pragma unroll
      for (int i = 0; i < 2; ++i) {
        const int col = (2*w + i)*16 + n;
        #pragma unroll
        for (int rr = 0; rr < 4; ++rr)
          hxA[hxi(q*4 + rr, col)] = f2b(hnew[i][rr]);
      }
    }
    __syncthreads();                 // B2: h(t) complete
  }

  // tail: pred(NSTEPS-1) from final h
  if (IS_DEC && w == 0) {
    short8 afx[8];
    #pragma unroll
    for (int k0 = 0; k0 < 8; ++k0)
      afx[k0] = *(const short8*)&hxA[(k0*64 + lane)*8];
    f32x4 lp = {0,0,0,0};
    #pragma unroll
    for (int k0 = 0; k0 < 8; ++k0) {
      const short8 lf = *(const short8*)&lwfc[(k0*5 + ((n==0) ? q : 4))*8];
      lp = __builtin_amdgcn_mfma_f32_16x16x32_bf16(afx[k0], lf, lp, 0,0,0);
    }
    if (n == 0 && q < 2) {
      #pragma unroll
      for (int rr = 0; rr < 4; ++rr)
        predp[(b0 + q*4 + rr)*54 + (NSTEPS-1)] = lp[rr] + lb;
    }
  }
}

// ===================== encoder + latent (fused) =====================
__global__ __launch_bounds__(512, 2) void enc_lat(
    const u16* __restrict__ wsB,
    const float* __restrict__ bih, const float* __restrict__ bhh,
    const float* __restrict__ X,
    const float* __restrict__ Wmu, const float* __restrict__ bmu,
    const float* __restrict__ Wsd, const float* __restrict__ bsd,
    const float* __restrict__ eps,
    float* __restrict__ z, float* __restrict__ out_lv, float* __restrict__ out_mu)
{
  extern __shared__ char smem[];
  u16* Blds = (u16*)smem;
  u16* hxA  = Blds + BLDS_U16;
  u16* xA   = hxA + HXA_U16;
  u16* lwfc = xA + XA_U16;
  const int b0 = blockIdx.y * 8;
  gru_body<10, false>(hxA, xA, Blds, lwfc, wsB + (size_t)32*SER_STRIDE,
                      bih, bhh, X, nullptr, nullptr, nullptr, nullptr, b0);
  __syncthreads();
  // latent: mu/lv/z for batches b0..b0+7 from bf16 h in hxA rows 0..7
  const int tid = threadIdx.x;
  const int j = tid & 255, half = tid >> 8;
  float am[4] = {0,0,0,0}, as[4] = {0,0,0,0};
  const float* wmrow = Wmu + j*256;
  const float* wsrow = Wsd + j*256;
  #pragma unroll 2
  for (int c0 = 0; c0 < 256; c0 += 8) {
    float4 wm0 = *(const float4*)&wmrow[c0];
    float4 wm1 = *(const float4*)&wmrow[c0+4];
    float4 ws0 = *(const float4*)&wsrow[c0];
    float4 ws1 = *(const float4*)&wsrow[c0+4];
    #pragma unroll
    for (int mm = 0; mm < 4; ++mm) {
      const u16* hp = &hxA[hxi(half*4 + mm, c0)];  // c0 % 8 == 0 -> 8 contiguous
      float h0x=b2f(hp[0]), h0y=b2f(hp[1]), h0z=b2f(hp[2]), h0w=b2f(hp[3]);
      float h1x=b2f(hp[4]), h1y=b2f(hp[5]), h1z=b2f(hp[6]), h1w=b2f(hp[7]);
      am[mm] += wm0.x*h0x + wm0.y*h0y + wm0.z*h0z + wm0.w*h0w
              + wm1.x*h1x + wm1.y*h1y + wm1.z*h1z + wm1.w*h1w;
      as[mm] += ws0.x*h0x + ws0.y*h0y + ws0.z*h0z + ws0.w*h0w
              + ws1.x*h1x + ws1.y*h1y + ws1.z*h1z + ws1.w*h1w;
    }
  }
  #pragma unroll
  for (int mm = 0; mm < 4; ++mm) {
    const int b = b0 + half*4 + mm;
    const float mu = am[mm] + bmu[j];
    const float lv = as[mm] + bsd[j];
    const float zv = mu + __expf(0.5f*lv) * eps[b*256 + j];
    z[b*256 + j]      = zv;
    out_lv[b*256 + j] = lv;
    out_mu[b*256 + j] = mu;
  }
}

// ===================== decoder =====================
// grid (32 series, 8 batch-slices): linear id = p + 32*s -> XCD = p%8 (L2 locality)
__global__ __launch_bounds__(512, 2) void dec_mfma(
    const u16* __restrict__ wsB,
    const float* __restrict__ bih, const float* __restrict__ bhh,
    const float* __restrict__ X, const float* __restrict__ z,
    const float* __restrict__ lin_w, const float* __restrict__ lin_b,
    float* __restrict__ pred)
{
  extern __shared__ char smem[];
  u16* Blds = (u16*)smem;
  u16* hxA  = Blds + BLDS_U16;
  u16* xA   = hxA + HXA_U16;
  u16* lwfc = xA + XA_U16;
  const int p = blockIdx.x;
  const int b0 = blockIdx.y * 8;
  gru_body<54, true>(hxA, xA, Blds, lwfc, wsB + (size_t)p*SER_STRIDE,
                     bih + p*768, bhh + p*768, X, z,
                     lin_w + p*256, lin_b + p, pred + p*3456, b0);
}

extern "C" void kernel_launch(void* const* d_in, const int* in_sizes, int n_in,
                              void* d_out, int out_size, void* d_ws, size_t ws_size,
                              hipStream_t stream) {
  const float* X        = (const float*)d_in[0];
  const float* eps      = (const float*)d_in[1];
  const float* Wih_enc  = (const float*)d_in[2];
  const float* Whh_enc  = (const float*)d_in[3];
  const float* bih_enc  = (const float*)d_in[4];
  const float* bhh_enc  = (const float*)d_in[5];
  const float* fc_mu_w  = (const float*)d_in[6];
  const float* fc_mu_b  = (const float*)d_in[7];
  const float* fc_std_w = (const float*)d_in[8];
  const float* fc_std_b = (const float*)d_in[9];
  const float* Wih_dec  = (const float*)d_in[10];
  const float* Whh_dec  = (const float*)d_in[11];
  const float* bih_dec  = (const float*)d_in[12];
  const float* bhh_dec  = (const float*)d_in[13];
  const float* lin_w    = (const float*)d_in[14];
  const float* lin_b    = (const float*)d_in[15];

  float* out    = (float*)d_out;
  float* pred   = out;              // [32][64][54][1] = 110592
  float* out_lv = out + 110592;     // [1][64][256]
  float* out_mu = out + 126976;     // [1][64][256]

  u16*   wsB = (u16*)d_ws;                                   // 33 * 221184 u16
  float* z   = (float*)((char*)d_ws + (size_t)33*SER_STRIDE*2);  // [64][256] fp32

  (void)hipFuncSetAttribute((const void*)enc_lat,
      hipFuncAttributeMaxDynamicSharedMemorySize, SMEM_BYTES);
  (void)hipFuncSetAttribute((const void*)dec_mfma,
      hipFuncAttributeMaxDynamicSharedMemorySize, SMEM_BYTES);

  pack_kernel<<<dim3(432, 33), 64, 0, stream>>>(Wih_dec, Whh_dec, Wih_enc, Whh_enc, wsB);
  enc_lat<<<dim3(1, 8), 512, SMEM_BYTES, stream>>>(
      wsB, bih_enc, bhh_enc, X,
      fc_mu_w, fc_mu_b, fc_std_w, fc_std_b, eps, z, out_lv, out_mu);
  dec_mfma<<<dim3(32, 8), 512, SMEM_BYTES, stream>>>(
      wsB, bih_dec, bhh_dec, X, z, lin_w, lin_b, pred);
}

// Round 8
// 280.449 us; speedup vs baseline: 8.0362x; 1.1680x over previous
//
#include <hip/hip_runtime.h>

typedef unsigned int u32;
typedef unsigned short u16;
typedef __attribute__((ext_vector_type(8))) short short8;
typedef __attribute__((ext_vector_type(4))) float f32x4;

#define DEV static __device__ __forceinline__

DEV float b2f(u16 v){ union{u32 u; float f;} c; c.u = ((u32)v) << 16; return c.f; }
DEV u16 f2b(float f){ union{float ff; u32 u;} c; c.ff = f; return (u16)((c.u + 0x7fffu + ((c.u >> 16) & 1u)) >> 16); }
DEV float sigm(float x){ return 1.f/(1.f + __expf(-x)); }
DEV float tanh_(float x){ float e = __expf(-2.f*x); return (1.f-e)/(1.f+e); }

// dims: B=64, T=64, P=32, H=256, 3H=768.
// Packed B in ws: per series: 48 N-tiles x 9 K-tiles x 64 lanes x 8 bf16.
#define SER_STRIDE 221184   // u16 per series

// LDS: Blds (K6,K7,K8: 48nt x 3 x 1KB) | hA (2 parities x 8k0 x 32chunks x 8 u16)
//      | xA (2 parities x 256 u16) | lwfc (256 u16)
// h rows 8..15 are never stored: lanes n>=8 re-read row n&7 (broadcast); MFMA D rows
// 8..15 become duplicates of 0..7 and are never consumed.
#define BLDS_U16 (48*3*64*8)
#define HA_U16   (2*2048)
#define XAB_U16  (2*256)
#define LWF_U16  256
#define SMEM_BYTES ((BLDS_U16 + HA_U16 + XAB_U16 + LWF_U16)*2)

// element (m in 0..7, c in 0..255) -> u16 index within one hA parity
DEV int hxi(int m, int c){ return (((c>>5)*32) + (((c>>3)&3)*8) + m)*8 + (c&7); }

// ===================== fragment pack (fp32 -> bf16 frags, once) =====================
__global__ __launch_bounds__(256) void pack_kernel(
    const float* __restrict__ WihD, const float* __restrict__ WhhD,
    const float* __restrict__ WihE, const float* __restrict__ WhhE,
    u16* __restrict__ wsB)
{
  const int ps = blockIdx.y;           // 0..31 dec series, 32 = encoder
  const int f  = blockIdx.x*4 + (threadIdx.x >> 6);   // n0*9 + k, 0..431
  const int n0 = f / 9, k = f - n0*9;
  const int lane = threadIdx.x & 63;
  const int n = lane & 15, q = lane >> 4;
  const int row = n0*16 + n;
  const float* Whh = (ps < 32) ? WhhD + ps*196608 : WhhE;
  const float* Wih = (ps < 32) ? WihD + ps*24576  : WihE;
  const float* src = (k < 8) ? (Whh + row*256 + k*32 + q*8) : (Wih + row*32 + q*8);
  u32 wd[4];
  #pragma unroll
  for (int j = 0; j < 4; ++j) {
    u16 lo = f2b(src[2*j]);
    u16 hi = f2b(src[2*j+1]);
    wd[j] = (u32)lo | ((u32)hi << 16);
  }
  *(uint4*)(wsB + (((size_t)ps*432 + f)*64 + lane)*8) = make_uint4(wd[0], wd[1], wd[2], wd[3]);
}

// ============ GRU body: 512 thr = 8 waves, M=8 batches, N=768 gate rows ============
// wave w owns hidden cols [32w, 32w+32) = col-tiles {2w, 2w+1}.
// B: K0..5 VGPR-resident (36 frags, packed loads + asm pin); K6,K7,K8 in LDS.
// One barrier per step (h parity double-buffer). Epilogue: shfl_xor(32) redistributes
// i=1 rows to lanes q>=2 so all 64 lanes do useful pointwise work; hold in registers.
template<int NSTEPS, bool IS_DEC>
DEV void gru_body(u16* hA, u16* xA, u16* Blds, u16* lwfc,
                  const u16* __restrict__ Bp,
                  const float* __restrict__ bihP, const float* __restrict__ bhhP,
                  const float* __restrict__ X, const float* __restrict__ z0,
                  const float* __restrict__ lwp, const float* __restrict__ lbp,
                  float* __restrict__ predp, int b0)
{
  const int tid = threadIdx.x;
  const int w = tid >> 6, lane = tid & 63;
  const int n = lane & 15, q = lane >> 4;
  const int isel  = q >> 1;                 // epilogue col-tile for this lane
  const int mbase = (q & 1) * 4;            // epilogue rows mbase..mbase+3
  const int colS  = (2*w + isel)*16 + n;    // epilogue hidden col

  // zero both h parities + both x parities (contiguous)
  for (int idx = tid; idx < (HA_U16 + XAB_U16)/2; idx += 512)
    ((u32*)hA)[idx] = 0;
  __syncthreads();

  if (IS_DEC) {                    // h(0) = z into parity 0 (bf16 frag-packed)
    const int m = tid >> 6, c0 = (tid*4) & 255;
    float4 v = *(const float4*)&z0[(b0+m)*256 + c0];
    const int base = hxi(m, c0);
    hA[base]   = f2b(v.x); hA[base+1] = f2b(v.y);
    hA[base+2] = f2b(v.z); hA[base+3] = f2b(v.w);
  } else if (tid < 256) {          // x(0) into parity 0
    const int m = tid >> 5, c = tid & 31;
    xA[((c>>3)*8 + m)*8 + (c&7)] = f2b(X[(b0+m)*2048 + c]);
  }
  if (IS_DEC && tid < 256)
    lwfc[tid] = f2b(lwp[tid]);     // identity mapping to frag layout

  // stage Blds: K6,K7,K8 frags for all 48 ntiles — pure uint4 copies
  #pragma unroll
  for (int r = 0; r < 18; ++r) {
    const int g = r*512 + tid;     // 0..9215 uint4s
    const int frag = g >> 6, e = g & 63;
    const int nt = frag / 3, kk = frag - nt*3;
    ((uint4*)Blds)[g] = ((const uint4*)Bp)[((size_t)nt*9 + 6 + kk)*64 + e];
  }

  // resident B: K0..5 for wave's 6 N-tiles — pure short8 loads + pin
  short8 Bres[36];
  #pragma unroll
  for (int i = 0; i < 2; ++i)
    #pragma unroll
    for (int g = 0; g < 3; ++g)
      #pragma unroll
      for (int k = 0; k < 6; ++k)
        Bres[(i*3+g)*6 + k] =
          *(const short8*)(Bp + (((size_t)(g*16 + 2*w + i)*9 + k)*64 + lane)*8);
  #pragma unroll
  for (int r = 0; r < 36; ++r)
    asm volatile("" : "+v"(Bres[r]));

  // epilogue-lane biases (only for this lane's assigned col)
  const float brS  = bihP[colS]     + bhhP[colS];
  const float bzS  = bihP[256+colS] + bhhP[256+colS];
  const float bnxS = bihP[512+colS];
  const float bnhS = bhhP[512+colS];
  const float lb = IS_DEC ? lbp[0] : 0.f;

  // hold in registers (same bf16 rounding the A-fragments see)
  float hold[4];
  #pragma unroll
  for (int rr = 0; rr < 4; ++rr)
    hold[rr] = IS_DEC ? b2f(f2b(z0[(b0 + mbase + rr)*256 + colS])) : 0.f;

  // write base for this lane's h column (within a parity)
  const int wbase = hxi(mbase, colS);
  __syncthreads();

  #pragma unroll 1
  for (int t = 0; t < NSTEPS; ++t) {
    const int par = t & 1;
    u16* hP = hA + par*2048;

    // x(t+1): issue global load early
    float xv = 0.f;
    const bool doX = (t+1 < NSTEPS) && (tid < 256);
    const int xm = tid >> 5, xc = tid & 31;
    if (doX) xv = X[(b0+xm)*2048 + (IS_DEC ? (t+10) : (t+1))*32 + xc];

    // A-fragments of [h(t-1) | x(t)] — lanes n>=8 re-read row n&7 (broadcast)
    short8 af[9];
    #pragma unroll
    for (int k0 = 0; k0 < 8; ++k0)
      af[k0] = *(const short8*)&hP[(k0*32 + q*8 + (n&7))*8];
    af[8] = *(const short8*)&xA[par*256 + (q*8 + (n&7))*8];

    // lin-projection of h(t-1) -> pred(t-1) via MFMA (wave 0, t>=1)
    if (IS_DEC && w == 0 && t > 0) {
      f32x4 lp = {0,0,0,0};
      #pragma unroll
      for (int k0 = 0; k0 < 8; ++k0) {
        const short8 lf = *(const short8*)&lwfc[(k0*4 + q)*8];
        lp = __builtin_amdgcn_mfma_f32_16x16x32_bf16(af[k0], lf, lp, 0,0,0);
      }
      if (n == 0 && q < 2) {
        #pragma unroll
        for (int rr = 0; rr < 4; ++rr)
          predp[(b0 + q*4 + rr)*54 + (t-1)] = lp[rr] + lb;
      }
    }

    // stage x(t+1) into opposite parity
    if (doX) xA[(par^1)*256 + ((xc>>3)*8 + xm)*8 + (xc&7)] = f2b(xv);

    // gate GEMMs
    f32x4 accr[2], accz[2], accnh[2], accnx[2];
    #pragma unroll
    for (int i = 0; i < 2; ++i) {
      const int ntr = 2*w + i, ntz = 16 + 2*w + i, ntn = 32 + 2*w + i;
      f32x4 ar={0,0,0,0}, az={0,0,0,0}, anh={0,0,0,0}, anx={0,0,0,0};
      const short8 b6r = *(const short8*)&Blds[((ntr*3+0)*64+lane)*8];
      const short8 b7r = *(const short8*)&Blds[((ntr*3+1)*64+lane)*8];
      const short8 b8r = *(const short8*)&Blds[((ntr*3+2)*64+lane)*8];
      const short8 b6z = *(const short8*)&Blds[((ntz*3+0)*64+lane)*8];
      const short8 b7z = *(const short8*)&Blds[((ntz*3+1)*64+lane)*8];
      const short8 b8z = *(const short8*)&Blds[((ntz*3+2)*64+lane)*8];
      const short8 b6n = *(const short8*)&Blds[((ntn*3+0)*64+lane)*8];
      const short8 b7n = *(const short8*)&Blds[((ntn*3+1)*64+lane)*8];
      const short8 b8n = *(const short8*)&Blds[((ntn*3+2)*64+lane)*8];
      #pragma unroll
      for (int k = 0; k < 6; ++k) {
        ar  = __builtin_amdgcn_mfma_f32_16x16x32_bf16(af[k], Bres[(i*3+0)*6+k], ar, 0,0,0);
        az  = __builtin_amdgcn_mfma_f32_16x16x32_bf16(af[k], Bres[(i*3+1)*6+k], az, 0,0,0);
        anh = __builtin_amdgcn_mfma_f32_16x16x32_bf16(af[k], Bres[(i*3+2)*6+k], anh, 0,0,0);
      }
      ar  = __builtin_amdgcn_mfma_f32_16x16x32_bf16(af[6], b6r, ar, 0,0,0);
      ar  = __builtin_amdgcn_mfma_f32_16x16x32_bf16(af[7], b7r, ar, 0,0,0);
      ar  = __builtin_amdgcn_mfma_f32_16x16x32_bf16(af[8], b8r, ar, 0,0,0);
      az  = __builtin_amdgcn_mfma_f32_16x16x32_bf16(af[6], b6z, az, 0,0,0);
      az  = __builtin_amdgcn_mfma_f32_16x16x32_bf16(af[7], b7z, az, 0,0,0);
      az  = __builtin_amdgcn_mfma_f32_16x16x32_bf16(af[8], b8z, az, 0,0,0);
      anh = __builtin_amdgcn_mfma_f32_16x16x32_bf16(af[6], b6n, anh, 0,0,0);
      anh = __builtin_amdgcn_mfma_f32_16x16x32_bf16(af[7], b7n, anh, 0,0,0);
      anx = __builtin_amdgcn_mfma_f32_16x16x32_bf16(af[8], b8n, anx, 0,0,0);
      accr[i] = ar; accz[i] = az; accnh[i] = anh; accnx[i] = anx;
    }

    // redistribute i=1 rows 0..7 to lanes q>=2; every lane does one 4-row epilogue
    u16* hW = hA + (par^1)*2048;
    #pragma unroll
    for (int rr = 0; rr < 4; ++rr) {
      const float r1  = __shfl_xor(accr[1][rr],  32, 64);
      const float z1  = __shfl_xor(accz[1][rr],  32, 64);
      const float nh1 = __shfl_xor(accnh[1][rr], 32, 64);
      const float nx1 = __shfl_xor(accnx[1][rr], 32, 64);
      const float arv  = (q >= 2) ? r1  : accr[0][rr];
      const float azv  = (q >= 2) ? z1  : accz[0][rr];
      const float anhv = (q >= 2) ? nh1 : accnh[0][rr];
      const float anxv = (q >= 2) ? nx1 : accnx[0][rr];
      const float rg = sigm(arv + brS);
      const float zg = sigm(azv + bzS);
      const float nv = tanh_(anxv + bnxS + rg*(anhv + bnhS));
      const float hn = (1.f - zg)*nv + zg*hold[rr];
      const u16 hb = f2b(hn);
      hold[rr] = b2f(hb);          // keep register copy consistent with LDS bf16
      hW[wbase + rr*8] = hb;
    }
    __syncthreads();               // single barrier: writes(par^1) visible, reads(par) done
  }

  // tail: pred(NSTEPS-1) from final h (parity NSTEPS&1)
  if (IS_DEC && w == 0) {
    const u16* hF = hA + (NSTEPS&1)*2048;
    f32x4 lp = {0,0,0,0};
    #pragma unroll
    for (int k0 = 0; k0 < 8; ++k0) {
      const short8 a = *(const short8*)&hF[(k0*32 + q*8 + (n&7))*8];
      const short8 lf = *(const short8*)&lwfc[(k0*4 + q)*8];
      lp = __builtin_amdgcn_mfma_f32_16x16x32_bf16(a, lf, lp, 0,0,0);
    }
    if (n == 0 && q < 2) {
      #pragma unroll
      for (int rr = 0; rr < 4; ++rr)
        predp[(b0 + q*4 + rr)*54 + (NSTEPS-1)] = lp[rr] + lb;
    }
  }
}

// ===================== encoder + latent (fused) =====================
__global__ __launch_bounds__(512, 2) void enc_lat(
    const u16* __restrict__ wsB,
    const float* __restrict__ bih, const float* __restrict__ bhh,
    const float* __restrict__ X,
    const float* __restrict__ Wmu, const float* __restrict__ bmu,
    const float* __restrict__ Wsd, const float* __restrict__ bsd,
    const float* __restrict__ eps,
    float* __restrict__ z, float* __restrict__ out_lv, float* __restrict__ out_mu)
{
  extern __shared__ char smem[];
  u16* Blds = (u16*)smem;
  u16* hA   = Blds + BLDS_U16;
  u16* xA   = hA + HA_U16;
  u16* lwfc = xA + XAB_U16;
  const int b0 = blockIdx.y * 8;
  gru_body<10, false>(hA, xA, Blds, lwfc, wsB + (size_t)32*SER_STRIDE,
                      bih, bhh, X, nullptr, nullptr, nullptr, nullptr, b0);
  __syncthreads();
  // latent from final h (parity 0 for NSTEPS=10)
  const int tid = threadIdx.x;
  const int j = tid & 255, half = tid >> 8;
  float am[4] = {0,0,0,0}, as[4] = {0,0,0,0};
  const float* wmrow = Wmu + j*256;
  const float* wsrow = Wsd + j*256;
  const u16* hF = hA + ((10)&1)*2048;
  #pragma unroll 2
  for (int c0 = 0; c0 < 256; c0 += 8) {
    float4 wm0 = *(const float4*)&wmrow[c0];
    float4 wm1 = *(const float4*)&wmrow[c0+4];
    float4 ws0 = *(const float4*)&wsrow[c0];
    float4 ws1 = *(const float4*)&wsrow[c0+4];
    #pragma unroll
    for (int mm = 0; mm < 4; ++mm) {
      const u16* hp = &hF[hxi(half*4 + mm, c0)];   // 8 contiguous u16
      float h0x=b2f(hp[0]), h0y=b2f(hp[1]), h0z=b2f(hp[2]), h0w=b2f(hp[3]);
      float h1x=b2f(hp[4]), h1y=b2f(hp[5]), h1z=b2f(hp[6]), h1w=b2f(hp[7]);
      am[mm] += wm0.x*h0x + wm0.y*h0y + wm0.z*h0z + wm0.w*h0w
              + wm1.x*h1x + wm1.y*h1y + wm1.z*h1z + wm1.w*h1w;
      as[mm] += ws0.x*h0x + ws0.y*h0y + ws0.z*h0z + ws0.w*h0w
              + ws1.x*h1x + ws1.y*h1y + ws1.z*h1z + ws1.w*h1w;
    }
  }
  #pragma unroll
  for (int mm = 0; mm < 4; ++mm) {
    const int b = b0 + half*4 + mm;
    const float mu = am[mm] + bmu[j];
    const float lv = as[mm] + bsd[j];
    const float zv = mu + __expf(0.5f*lv) * eps[b*256 + j];
    z[b*256 + j]      = zv;
    out_lv[b*256 + j] = lv;
    out_mu[b*256 + j] = mu;
  }
}

// ===================== decoder =====================
// grid (32 series, 8 batch-slices): linear id = p + 32*s -> XCD = p%8 (L2 locality)
__global__ __launch_bounds__(512, 2) void dec_mfma(
    const u16* __restrict__ wsB,
    const float* __restrict__ bih, const float* __restrict__ bhh,
    const float* __restrict__ X, const float* __restrict__ z,
    const float* __restrict__ lin_w, const float* __restrict__ lin_b,
    float* __restrict__ pred)
{
  extern __shared__ char smem[];
  u16* Blds = (u16*)smem;
  u16* hA   = Blds + BLDS_U16;
  u16* xA   = hA + HA_U16;
  u16* lwfc = xA + XAB_U16;
  const int p = blockIdx.x;
  const int b0 = blockIdx.y * 8;
  gru_body<54, true>(hA, xA, Blds, lwfc, wsB + (size_t)p*SER_STRIDE,
                     bih + p*768, bhh + p*768, X, z,
                     lin_w + p*256, lin_b + p, pred + p*3456, b0);
}

extern "C" void kernel_launch(void* const* d_in, const int* in_sizes, int n_in,
                              void* d_out, int out_size, void* d_ws, size_t ws_size,
                              hipStream_t stream) {
  const float* X        = (const float*)d_in[0];
  const float* eps      = (const float*)d_in[1];
  const float* Wih_enc  = (const float*)d_in[2];
  const float* Whh_enc  = (const float*)d_in[3];
  const float* bih_enc  = (const float*)d_in[4];
  const float* bhh_enc  = (const float*)d_in[5];
  const float* fc_mu_w  = (const float*)d_in[6];
  const float* fc_mu_b  = (const float*)d_in[7];
  const float* fc_std_w = (const float*)d_in[8];
  const float* fc_std_b = (const float*)d_in[9];
  const float* Wih_dec  = (const float*)d_in[10];
  const float* Whh_dec  = (const float*)d_in[11];
  const float* bih_dec  = (const float*)d_in[12];
  const float* bhh_dec  = (const float*)d_in[13];
  const float* lin_w    = (const float*)d_in[14];
  const float* lin_b    = (const float*)d_in[15];

  float* out    = (float*)d_out;
  float* pred   = out;              // [32][64][54][1] = 110592
  float* out_lv = out + 110592;     // [1][64][256]
  float* out_mu = out + 126976;     // [1][64][256]

  u16*   wsB = (u16*)d_ws;                                       // 33 * 221184 u16
  float* z   = (float*)((char*)d_ws + (size_t)33*SER_STRIDE*2);  // [64][256] fp32

  (void)hipFuncSetAttribute((const void*)enc_lat,
      hipFuncAttributeMaxDynamicSharedMemorySize, SMEM_BYTES);
  (void)hipFuncSetAttribute((const void*)dec_mfma,
      hipFuncAttributeMaxDynamicSharedMemorySize, SMEM_BYTES);

  pack_kernel<<<dim3(108, 33), 256, 0, stream>>>(Wih_dec, Whh_dec, Wih_enc, Whh_enc, wsB);
  enc_lat<<<dim3(1, 8), 512, SMEM_BYTES, stream>>>(
      wsB, bih_enc, bhh_enc, X,
      fc_mu_w, fc_mu_b, fc_std_w, fc_std_b, eps, z, out_lv, out_mu);
  dec_mfma<<<dim3(32, 8), 512, SMEM_BYTES, stream>>>(
      wsB, bih_dec, bhh_dec, X, z, lin_w, lin_b, pred);
}